// Round 4
// baseline (691.815 us; speedup 1.0000x reference)
//
#include <hip/hip_runtime.h>
#include <stdint.h>

// ---- workspace layout (float offsets) ----
#define WS_FQ    0u          // f quantized u8 [32][8192] = 65536 floats
#define WS_BN    65536u      // A1[64] B1[64] A2[128] B2[128]
#define WS_NR    65920u      // nr[32] dr[32]
#define WS_PRED  65984u      // int
#define WS_CNT   65985u      // int[10]
#define WS_FMAX  65995u      // float (atomicMax as int)
#define WS_X     66048u      // overlay region:
#define WS_P1    WS_X                  // conv: [32][64][16][16] = 524288
#define WS_W2T   (WS_X + 524288u)      // conv: [9][64][128]     = 73728
#define WS_P2F   (WS_X + 598016u)      // conv: [32][8192] f32   = 262144
#define WS_L1P   WS_X                  // knn:  [8][32][20096]   = 5144576

__device__ __forceinline__ unsigned sad4(unsigned a, unsigned b, unsigned c) {
#if __has_builtin(__builtin_amdgcn_sad_u8)
  return __builtin_amdgcn_sad_u8(a, b, c);
#else
  unsigned d;
  asm("v_sad_u8 %0, %1, %2, %3" : "=v"(d) : "v"(a), "v"(b), "v"(c));
  return d;
#endif
}

// ---------------- k0a: init + BN fold ----------------
__global__ __launch_bounds__(256) void k0a_init(
    const float* __restrict__ c1b, const float* __restrict__ g1,
    const float* __restrict__ be1, const float* __restrict__ m1,
    const float* __restrict__ v1,
    const float* __restrict__ c2b, const float* __restrict__ g2,
    const float* __restrict__ be2, const float* __restrict__ m2,
    const float* __restrict__ v2,
    float* __restrict__ ws)
{
  int tid = threadIdx.x;
  if (tid < 64) ws[WS_NR + tid] = 0.f;
  if (tid >= 192 && tid < 202) ((int*)(ws + WS_CNT))[tid - 192] = 0;
  if (tid == 202) ws[WS_FMAX] = 2.0f;
  if (tid < 64) {
    float A = g1[tid] * __frsqrt_rn(v1[tid] + 1e-5f);
    ws[WS_BN + tid] = A;
    ws[WS_BN + 64 + tid] = (c1b[tid] - m1[tid]) * A + be1[tid];
  } else if (tid < 192) {
    int c = tid - 64;
    float A = g2[c] * __frsqrt_rn(v2[c] + 1e-5f);
    ws[WS_BN + 128 + c] = A;
    ws[WS_BN + 256 + c] = (c2b[c] - m2[c]) * A + be2[c];
  }
}

// ---------------- k0b: label histogram (20 blocks) ----------------
__global__ __launch_bounds__(256) void k0b_hist(const int* __restrict__ labels,
                                                float* __restrict__ ws)
{
  __shared__ int cnt[10];
  int tid = threadIdx.x;
  if (tid < 10) cnt[tid] = 0;
  __syncthreads();
  int i0 = (blockIdx.x * 256 + tid) * 4;
  if (i0 + 3 < 20000) {
    int4 v = *(const int4*)(labels + i0);
    atomicAdd(&cnt[v.x], 1);
    atomicAdd(&cnt[v.y], 1);
    atomicAdd(&cnt[v.z], 1);
    atomicAdd(&cnt[v.w], 1);
  }
  __syncthreads();
  if (tid < 10) atomicAdd((int*)(ws + WS_CNT) + tid, cnt[tid]);
}

// ---------------- k0c: mode ----------------
__global__ void k0c_mode(float* __restrict__ ws)
{
  if (threadIdx.x == 0) {
    const int* cnt = (const int*)(ws + WS_CNT);
    int best = 0;
    for (int c = 1; c < 10; ++c) if (cnt[c] > cnt[best]) best = c;
    ((int*)(ws + WS_PRED))[0] = best;
  }
}

// ---------------- k1: transpose conv2 weights -> [kk][ci][co] ----------------
__global__ __launch_bounds__(256) void k1_w2t(const float* __restrict__ w2,
                                              float* __restrict__ w2t)
{
  int idx = blockIdx.x * 256 + threadIdx.x;
  if (idx >= 73728) return;
  int co = idx / 576, r = idx % 576, ci = r / 9, kk = r % 9;
  w2t[(kk * 64 + ci) * 128 + co] = w2[idx];
}

// ---------------- k2: conv1 + BN + ReLU + 2x2 maxpool (scalar weights) ----------------
__global__ __launch_bounds__(256) void k2_conv1(
    const float* __restrict__ x, const float* __restrict__ w1,
    const float* __restrict__ wsc, float* __restrict__ p1)
{
  __shared__ float xs[3 * 34 * 34];
  int tid = threadIdx.x;
  int b = blockIdx.x >> 4, cog = blockIdx.x & 15;

  for (int idx = tid; idx < 3 * 34 * 34; idx += 256) {
    int ci = idx / 1156, r = idx % 1156, yy = r / 34, xc = r % 34;
    int yg = yy - 1, xg = xc - 1;
    float v = 0.f;
    if ((unsigned)yg < 32u && (unsigned)xg < 32u)
      v = x[((b * 3 + ci) * 32 + yg) * 32 + xg];
    xs[idx] = v;
  }
  __syncthreads();

  int py = tid >> 4, px = tid & 15;
  float acc[4][4] = {};
#pragma unroll
  for (int ci = 0; ci < 3; ++ci)
#pragma unroll
    for (int ky = 0; ky < 3; ++ky)
#pragma unroll
      for (int kx = 0; kx < 3; ++kx) {
        const float* xp = &xs[ci * 1156 + (2 * py + ky) * 34 + (2 * px + kx)];
        float i00 = xp[0], i01 = xp[1], i10 = xp[34], i11 = xp[35];
#pragma unroll
        for (int c = 0; c < 4; ++c) {
          float wv = w1[cog * 108 + c * 27 + ci * 9 + ky * 3 + kx];  // uniform -> s_load
          acc[c][0] = fmaf(i00, wv, acc[c][0]);
          acc[c][1] = fmaf(i01, wv, acc[c][1]);
          acc[c][2] = fmaf(i10, wv, acc[c][2]);
          acc[c][3] = fmaf(i11, wv, acc[c][3]);
        }
      }
#pragma unroll
  for (int c = 0; c < 4; ++c) {
    int co = cog * 4 + c;
    float A = wsc[WS_BN + co], B = wsc[WS_BN + 64 + co];
    float v0 = fmaxf(fmaf(acc[c][0], A, B), 0.f);
    float v1 = fmaxf(fmaf(acc[c][1], A, B), 0.f);
    float v2 = fmaxf(fmaf(acc[c][2], A, B), 0.f);
    float v3 = fmaxf(fmaf(acc[c][3], A, B), 0.f);
    float m = fmaxf(fmaxf(v0, v1), fmaxf(v2, v3));
    p1[((b * 64 + co) * 16 + py) * 16 + px] = m;
  }
}

// ---------------- k3: conv2 + BN + ReLU + pool (scalar weights) ----------------
__global__ __launch_bounds__(256) void k3_conv2(
    const float* __restrict__ p1, const float* __restrict__ w2t,
    const float* __restrict__ wsc, float* __restrict__ p2f,
    float* __restrict__ out)
{
  __shared__ float in_s[32 * 324];  // 40.5 KB
  __shared__ float pb[4096];        // 16 KB pool buffer
  int tid = threadIdx.x;
  int b = blockIdx.x >> 3, cog = blockIdx.x & 7;
  int y = tid >> 4, xx = tid & 15;

  float acc[16];
#pragma unroll
  for (int c = 0; c < 16; ++c) acc[c] = 0.f;

  for (int h = 0; h < 2; ++h) {
    __syncthreads();
    for (int idx = tid; idx < 10368; idx += 256) {
      int ci = idx / 324, r = idx % 324, yy = r / 18, xc = r % 18;
      int yg = yy - 1, xg = xc - 1;
      float v = 0.f;
      if ((unsigned)yg < 16u && (unsigned)xg < 16u)
        v = p1[((b * 64 + h * 32 + ci) * 16 + yg) * 16 + xg];
      in_s[idx] = v;
    }
    __syncthreads();
    for (int ci = 0; ci < 32; ++ci) {
#pragma unroll
      for (int kk = 0; kk < 9; ++kk) {
        int ky = kk / 3, kx = kk % 3;
        float in = in_s[ci * 324 + (y + ky) * 18 + (xx + kx)];
        const float4* wp = (const float4*)(w2t + ((kk * 64 + h * 32 + ci) * 128 + cog * 16));
        float4 a0 = wp[0], a1 = wp[1], a2 = wp[2], a3 = wp[3];  // uniform -> s_load
        acc[0]  = fmaf(in, a0.x, acc[0]);  acc[1]  = fmaf(in, a0.y, acc[1]);
        acc[2]  = fmaf(in, a0.z, acc[2]);  acc[3]  = fmaf(in, a0.w, acc[3]);
        acc[4]  = fmaf(in, a1.x, acc[4]);  acc[5]  = fmaf(in, a1.y, acc[5]);
        acc[6]  = fmaf(in, a1.z, acc[6]);  acc[7]  = fmaf(in, a1.w, acc[7]);
        acc[8]  = fmaf(in, a2.x, acc[8]);  acc[9]  = fmaf(in, a2.y, acc[9]);
        acc[10] = fmaf(in, a2.z, acc[10]); acc[11] = fmaf(in, a2.w, acc[11]);
        acc[12] = fmaf(in, a3.x, acc[12]); acc[13] = fmaf(in, a3.y, acc[13]);
        acc[14] = fmaf(in, a3.z, acc[14]); acc[15] = fmaf(in, a3.w, acc[15]);
      }
    }
  }
  __syncthreads();
#pragma unroll
  for (int c = 0; c < 16; ++c) {
    int co = cog * 16 + c;
    float v = fmaxf(fmaf(acc[c], wsc[WS_BN + 128 + co], wsc[WS_BN + 256 + co]), 0.f);
    pb[c * 256 + y * 16 + xx] = v;
  }
  __syncthreads();
  if (tid < 64) {
    int py = tid >> 3, px = tid & 7;
#pragma unroll
    for (int c = 0; c < 16; ++c) {
      const float* q = &pb[c * 256 + (2 * py) * 16 + 2 * px];
      float m = fmaxf(fmaxf(q[0], q[1]), fmaxf(q[16], q[17]));
      int co = cog * 16 + c;
      int fi = b * 8192 + co * 64 + py * 8 + px;
      p2f[fi] = m;
      out[32 + fi] = m;
    }
  }
}

// ---------------- k3b: fmax over f ----------------
__global__ __launch_bounds__(256) void k3b_fmax(const float* __restrict__ p2f,
                                                float* __restrict__ ws)
{
  int idx = blockIdx.x * 256 + threadIdx.x;   // 65536 float4s exactly
  float4 v = *(const float4*)(p2f + idx * 4);
  float m = fmaxf(fmaxf(v.x, v.y), fmaxf(v.z, v.w));
#pragma unroll
  for (int off = 32; off > 0; off >>= 1) m = fmaxf(m, __shfl_xor(m, off));
  if ((threadIdx.x & 63) == 0) atomicMax((int*)(ws + WS_FMAX), __float_as_int(m));
}

// ---------------- k3c: quantize f -> u8 ----------------
__global__ __launch_bounds__(256) void k3c_quant(const float* __restrict__ p2f,
                                                 const float* __restrict__ wsc,
                                                 unsigned* __restrict__ fq)
{
  int wid = blockIdx.x * 256 + threadIdx.x;   // 65536 words exactly
  float kq = 255.0f / wsc[WS_FMAX];
  float4 v = *(const float4*)(p2f + wid * 4);
  unsigned q0 = (unsigned)fmaf(v.x, kq, 0.5f);
  unsigned q1 = (unsigned)fmaf(v.y, kq, 0.5f);
  unsigned q2 = (unsigned)fmaf(v.z, kq, 0.5f);
  unsigned q3 = (unsigned)fmaf(v.w, kq, 0.5f);
  fq[wid] = q0 | (q1 << 8) | (q2 << 16) | (q3 << 24);
}

// ---------------- k4: L1-kNN via v_sad_u8 ----------------
// grid = (157 n-tiles of 128, 8 d-splits of 1024). 4 waves; wave w owns dims
// [s*1024+w*256, +256) in chunks of 32. Per-wave LDS: f [32 rows][32B] u8 (1KB),
// n [128 rows][48B stride] u8 (6KB). Thread tile 8b x 8n, 2 sad-words per step.
__global__ __launch_bounds__(256, 4) void k4_knn(
    const float* __restrict__ nbr, const unsigned* __restrict__ fq,
    const float* __restrict__ wsc, float* __restrict__ l1p)
{
  __shared__ __align__(16) char smem[28672];
  const int tid = threadIdx.x;
  const int w = tid >> 6, lane = tid & 63;
  const int b_thr = lane >> 4;    // 0..3
  const int n_thr = lane & 15;    // 0..15
  const int n0 = blockIdx.x * 128;
  const int s = blockIdx.y;
  const int dbase = s * 1024 + w * 256;
  char* ft = smem + w * 7168;
  char* nt = ft + 1024;
  const float kq = 255.0f / wsc[WS_FMAX];

  unsigned acc[8][8];
#pragma unroll
  for (int i = 0; i < 8; ++i)
#pragma unroll
    for (int j = 0; j < 8; ++j) acc[i][j] = 0u;

#pragma unroll 1
  for (int ch = 0; ch < 8; ++ch) {
    const int dc = dbase + ch * 32;
    __syncthreads();
    // stage f tile: 32 rows x 8 words (already u8)
#pragma unroll
    for (int t = 0; t < 4; ++t) {
      int uu = t * 64 + lane;
      int row = uu >> 3, wd = uu & 7;
      unsigned v = fq[row * 2048 + (dc >> 2) + wd];
      *(unsigned*)(ft + row * 32 + wd * 4) = v;
    }
    // stage n tile: 128 rows x 32 dims fp32 -> u8 quantize+pack
#pragma unroll
    for (int t = 0; t < 16; ++t) {
      int uu = t * 64 + lane;
      int row = uu >> 3, g = uu & 7;
      int nn = n0 + row; if (nn > 19999) nn = 19999;
      float4 v = *(const float4*)(nbr + (size_t)nn * 8192 + dc + g * 4);
      unsigned q0 = (unsigned)fmaf(v.x, kq, 0.5f);
      unsigned q1 = (unsigned)fmaf(v.y, kq, 0.5f);
      unsigned q2 = (unsigned)fmaf(v.z, kq, 0.5f);
      unsigned q3 = (unsigned)fmaf(v.w, kq, 0.5f);
      *(unsigned*)(nt + row * 48 + g * 4) = q0 | (q1 << 8) | (q2 << 16) | (q3 << 24);
    }
    __syncthreads();
#pragma unroll
    for (int h = 0; h < 4; ++h) {      // 8 dims (2 sad-words) per h
      uint2 fv[8], nv[8];
#pragma unroll
      for (int i = 0; i < 8; ++i)
        fv[i] = *(const uint2*)(ft + (b_thr + 4 * i) * 32 + h * 8);
#pragma unroll
      for (int j = 0; j < 8; ++j)
        nv[j] = *(const uint2*)(nt + (n_thr + 16 * j) * 48 + h * 8);
#pragma unroll
      for (int i = 0; i < 8; ++i)
#pragma unroll
        for (int j = 0; j < 8; ++j)
          acc[i][j] = sad4(fv[i].y, nv[j].y, sad4(fv[i].x, nv[j].x, acc[i][j]));
    }
  }

  // cross-wave reduce, 4 quarters of 8 b-rows (16 KB overlay)
  unsigned* red = (unsigned*)smem;
  __syncthreads();
#pragma unroll 1
  for (int qt = 0; qt < 4; ++qt) {
#pragma unroll
    for (int ii = 0; ii < 2; ++ii) {
      int i = qt * 2 + ii;
      int brow8 = ii * 4 + b_thr;
#pragma unroll
      for (int j = 0; j < 8; ++j)
        red[(brow8 * 128 + n_thr + 16 * j) * 4 + w] = acc[i][j];
    }
    __syncthreads();
#pragma unroll
    for (int k = 0; k < 4; ++k) {
      int e = k * 256 + tid;
      uint4 v = *(const uint4*)(red + e * 4);
      int brow = qt * 8 + (e >> 7), n = e & 127;
      l1p[(s * 32 + brow) * 20096 + n0 + n] = (float)(v.x + v.y + v.z + v.w);
    }
    __syncthreads();
  }
}

// ---------------- k5: reduce splits, exp-weight, mask, accumulate nr/dr ----------------
__global__ __launch_bounds__(256) void k5_red(
    const float* __restrict__ l1p, const int* __restrict__ labels,
    const float* __restrict__ wsc, float* __restrict__ nrdr)
{
  int b = blockIdx.y;
  int n = blockIdx.x * 256 + (int)threadIdx.x;
  int pred = ((const int*)(wsc + WS_PRED))[0];
  float c = wsc[WS_FMAX] * (-1.0f / (255.0f * 1000.0f));
  float wgt = 0.f, mk = 0.f;
  if (n < 20000) {
    float L1 = 0.f;
#pragma unroll
    for (int s2 = 0; s2 < 8; ++s2) L1 += l1p[(s2 * 32 + b) * 20096 + n];
    wgt = __expf(L1 * c);
    if (labels[n] == pred) mk = wgt;
  }
#pragma unroll
  for (int off = 32; off > 0; off >>= 1) {
    wgt += __shfl_xor(wgt, off);
    mk  += __shfl_xor(mk, off);
  }
  if ((threadIdx.x & 63) == 0) {
    atomicAdd(&nrdr[b], mk);
    atomicAdd(&nrdr[32 + b], wgt);
  }
}

// ---------------- k6: final ratio ----------------
__global__ void k6_out(const float* __restrict__ nrdr, float* __restrict__ out)
{
  int t = threadIdx.x;
  if (t < 32) out[t] = nrdr[t] / nrdr[32 + t];
}

extern "C" void kernel_launch(void* const* d_in, const int* in_sizes, int n_in,
                              void* d_out, int out_size, void* d_ws, size_t ws_size,
                              hipStream_t stream)
{
  (void)in_sizes; (void)n_in; (void)out_size; (void)ws_size;
  const float* x    = (const float*)d_in[0];
  const float* w1   = (const float*)d_in[1];
  const float* c1b  = (const float*)d_in[2];
  const float* g1   = (const float*)d_in[3];
  const float* be1  = (const float*)d_in[4];
  const float* m1   = (const float*)d_in[5];
  const float* v1   = (const float*)d_in[6];
  const float* w2   = (const float*)d_in[7];
  const float* c2b  = (const float*)d_in[8];
  const float* g2   = (const float*)d_in[9];
  const float* be2  = (const float*)d_in[10];
  const float* m2   = (const float*)d_in[11];
  const float* v2   = (const float*)d_in[12];
  const float* nbrf = (const float*)d_in[13];
  const int* labels = (const int*)d_in[14];
  float* ws = (float*)d_ws;
  float* out = (float*)d_out;

  k0a_init<<<1, 256, 0, stream>>>(c1b, g1, be1, m1, v1, c2b, g2, be2, m2, v2, ws);
  k0b_hist<<<20, 256, 0, stream>>>(labels, ws);
  k0c_mode<<<1, 64, 0, stream>>>(ws);
  k1_w2t<<<288, 256, 0, stream>>>(w2, ws + WS_W2T);
  k2_conv1<<<512, 256, 0, stream>>>(x, w1, ws, ws + WS_P1);
  k3_conv2<<<256, 256, 0, stream>>>(ws + WS_P1, ws + WS_W2T, ws, ws + WS_P2F, out);
  k3b_fmax<<<256, 256, 0, stream>>>(ws + WS_P2F, ws);
  k3c_quant<<<256, 256, 0, stream>>>(ws + WS_P2F, ws, (unsigned*)(ws + WS_FQ));
  k4_knn<<<dim3(157, 8), 256, 0, stream>>>(nbrf, (const unsigned*)(ws + WS_FQ), ws, ws + WS_L1P);
  k5_red<<<dim3(79, 32), 256, 0, stream>>>(ws + WS_L1P, labels, ws, ws + WS_NR);
  k6_out<<<1, 64, 0, stream>>>(ws + WS_NR, out);
}

// Round 5
// 688.516 us; speedup vs baseline: 1.0048x; 1.0048x over previous
//
#include <hip/hip_runtime.h>
#include <stdint.h>

// ---- workspace layout (float offsets) ----
#define WS_FQ    0u          // f quantized u8 [32][8192] = 65536 floats
#define WS_BN    65536u      // A1[64] B1[64] A2[128] B2[128]
#define WS_NR    65920u      // nr[32] dr[32]
#define WS_PRED  65984u      // int
#define WS_CNT   65985u      // int[10]
#define WS_FMAX  65995u      // float (atomicMax as int)
#define WS_X     66048u      // overlay region:
#define WS_P1    WS_X                  // conv: [32][64][16][16] = 524288
#define WS_W2T   (WS_X + 524288u)      // conv: [9][64][128]     = 73728
#define WS_P2F   (WS_X + 598016u)      // conv: [32][8192] f32   = 262144
#define WS_L1P   WS_X                  // knn:  [8][32][20096]   = 5144576

__device__ __forceinline__ unsigned sad4(unsigned a, unsigned b, unsigned c) {
#if __has_builtin(__builtin_amdgcn_sad_u8)
  return __builtin_amdgcn_sad_u8(a, b, c);
#else
  unsigned d;
  asm("v_sad_u8 %0, %1, %2, %3" : "=v"(d) : "v"(a), "v"(b), "v"(c));
  return d;
#endif
}

// ---------------- k0a: init + BN fold ----------------
__global__ __launch_bounds__(256) void k0a_init(
    const float* __restrict__ c1b, const float* __restrict__ g1,
    const float* __restrict__ be1, const float* __restrict__ m1,
    const float* __restrict__ v1,
    const float* __restrict__ c2b, const float* __restrict__ g2,
    const float* __restrict__ be2, const float* __restrict__ m2,
    const float* __restrict__ v2,
    float* __restrict__ ws)
{
  int tid = threadIdx.x;
  if (tid < 64) ws[WS_NR + tid] = 0.f;
  if (tid >= 192 && tid < 202) ((int*)(ws + WS_CNT))[tid - 192] = 0;
  if (tid == 202) ws[WS_FMAX] = 2.0f;
  if (tid < 64) {
    float A = g1[tid] * __frsqrt_rn(v1[tid] + 1e-5f);
    ws[WS_BN + tid] = A;
    ws[WS_BN + 64 + tid] = (c1b[tid] - m1[tid]) * A + be1[tid];
  } else if (tid < 192) {
    int c = tid - 64;
    float A = g2[c] * __frsqrt_rn(v2[c] + 1e-5f);
    ws[WS_BN + 128 + c] = A;
    ws[WS_BN + 256 + c] = (c2b[c] - m2[c]) * A + be2[c];
  }
}

// ---------------- k0b: label histogram (20 blocks) ----------------
__global__ __launch_bounds__(256) void k0b_hist(const int* __restrict__ labels,
                                                float* __restrict__ ws)
{
  __shared__ int cnt[10];
  int tid = threadIdx.x;
  if (tid < 10) cnt[tid] = 0;
  __syncthreads();
  int i0 = (blockIdx.x * 256 + tid) * 4;
  if (i0 + 3 < 20000) {
    int4 v = *(const int4*)(labels + i0);
    atomicAdd(&cnt[v.x], 1);
    atomicAdd(&cnt[v.y], 1);
    atomicAdd(&cnt[v.z], 1);
    atomicAdd(&cnt[v.w], 1);
  }
  __syncthreads();
  if (tid < 10) atomicAdd((int*)(ws + WS_CNT) + tid, cnt[tid]);
}

// ---------------- k0c: mode ----------------
__global__ void k0c_mode(float* __restrict__ ws)
{
  if (threadIdx.x == 0) {
    const int* cnt = (const int*)(ws + WS_CNT);
    int best = 0;
    for (int c = 1; c < 10; ++c) if (cnt[c] > cnt[best]) best = c;
    ((int*)(ws + WS_PRED))[0] = best;
  }
}

// ---------------- k1: transpose conv2 weights -> [kk][ci][co] ----------------
__global__ __launch_bounds__(256) void k1_w2t(const float* __restrict__ w2,
                                              float* __restrict__ w2t)
{
  int idx = blockIdx.x * 256 + threadIdx.x;
  if (idx >= 73728) return;
  int co = idx / 576, r = idx % 576, ci = r / 9, kk = r % 9;
  w2t[(kk * 64 + ci) * 128 + co] = w2[idx];
}

// ---------------- k2: conv1 + BN + ReLU + 2x2 maxpool (scalar weights) ----------------
__global__ __launch_bounds__(256) void k2_conv1(
    const float* __restrict__ x, const float* __restrict__ w1,
    const float* __restrict__ wsc, float* __restrict__ p1)
{
  __shared__ float xs[3 * 34 * 34];
  int tid = threadIdx.x;
  int b = blockIdx.x >> 4, cog = blockIdx.x & 15;

  for (int idx = tid; idx < 3 * 34 * 34; idx += 256) {
    int ci = idx / 1156, r = idx % 1156, yy = r / 34, xc = r % 34;
    int yg = yy - 1, xg = xc - 1;
    float v = 0.f;
    if ((unsigned)yg < 32u && (unsigned)xg < 32u)
      v = x[((b * 3 + ci) * 32 + yg) * 32 + xg];
    xs[idx] = v;
  }
  __syncthreads();

  int py = tid >> 4, px = tid & 15;
  float acc[4][4] = {};
#pragma unroll
  for (int ci = 0; ci < 3; ++ci)
#pragma unroll
    for (int ky = 0; ky < 3; ++ky)
#pragma unroll
      for (int kx = 0; kx < 3; ++kx) {
        const float* xp = &xs[ci * 1156 + (2 * py + ky) * 34 + (2 * px + kx)];
        float i00 = xp[0], i01 = xp[1], i10 = xp[34], i11 = xp[35];
#pragma unroll
        for (int c = 0; c < 4; ++c) {
          float wv = w1[cog * 108 + c * 27 + ci * 9 + ky * 3 + kx];  // uniform -> s_load
          acc[c][0] = fmaf(i00, wv, acc[c][0]);
          acc[c][1] = fmaf(i01, wv, acc[c][1]);
          acc[c][2] = fmaf(i10, wv, acc[c][2]);
          acc[c][3] = fmaf(i11, wv, acc[c][3]);
        }
      }
#pragma unroll
  for (int c = 0; c < 4; ++c) {
    int co = cog * 4 + c;
    float A = wsc[WS_BN + co], B = wsc[WS_BN + 64 + co];
    float v0 = fmaxf(fmaf(acc[c][0], A, B), 0.f);
    float v1 = fmaxf(fmaf(acc[c][1], A, B), 0.f);
    float v2 = fmaxf(fmaf(acc[c][2], A, B), 0.f);
    float v3 = fmaxf(fmaf(acc[c][3], A, B), 0.f);
    float m = fmaxf(fmaxf(v0, v1), fmaxf(v2, v3));
    p1[((b * 64 + co) * 16 + py) * 16 + px] = m;
  }
}

// ---------------- k3: conv2 + BN + ReLU + pool (scalar weights) ----------------
__global__ __launch_bounds__(256) void k3_conv2(
    const float* __restrict__ p1, const float* __restrict__ w2t,
    const float* __restrict__ wsc, float* __restrict__ p2f,
    float* __restrict__ out)
{
  __shared__ float in_s[32 * 324];  // 40.5 KB
  __shared__ float pb[4096];        // 16 KB pool buffer
  int tid = threadIdx.x;
  int b = blockIdx.x >> 3, cog = blockIdx.x & 7;
  int y = tid >> 4, xx = tid & 15;

  float acc[16];
#pragma unroll
  for (int c = 0; c < 16; ++c) acc[c] = 0.f;

  for (int h = 0; h < 2; ++h) {
    __syncthreads();
    for (int idx = tid; idx < 10368; idx += 256) {
      int ci = idx / 324, r = idx % 324, yy = r / 18, xc = r % 18;
      int yg = yy - 1, xg = xc - 1;
      float v = 0.f;
      if ((unsigned)yg < 16u && (unsigned)xg < 16u)
        v = p1[((b * 64 + h * 32 + ci) * 16 + yg) * 16 + xg];
      in_s[idx] = v;
    }
    __syncthreads();
    for (int ci = 0; ci < 32; ++ci) {
#pragma unroll
      for (int kk = 0; kk < 9; ++kk) {
        int ky = kk / 3, kx = kk % 3;
        float in = in_s[ci * 324 + (y + ky) * 18 + (xx + kx)];
        const float4* wp = (const float4*)(w2t + ((kk * 64 + h * 32 + ci) * 128 + cog * 16));
        float4 a0 = wp[0], a1 = wp[1], a2 = wp[2], a3 = wp[3];  // uniform -> s_load
        acc[0]  = fmaf(in, a0.x, acc[0]);  acc[1]  = fmaf(in, a0.y, acc[1]);
        acc[2]  = fmaf(in, a0.z, acc[2]);  acc[3]  = fmaf(in, a0.w, acc[3]);
        acc[4]  = fmaf(in, a1.x, acc[4]);  acc[5]  = fmaf(in, a1.y, acc[5]);
        acc[6]  = fmaf(in, a1.z, acc[6]);  acc[7]  = fmaf(in, a1.w, acc[7]);
        acc[8]  = fmaf(in, a2.x, acc[8]);  acc[9]  = fmaf(in, a2.y, acc[9]);
        acc[10] = fmaf(in, a2.z, acc[10]); acc[11] = fmaf(in, a2.w, acc[11]);
        acc[12] = fmaf(in, a3.x, acc[12]); acc[13] = fmaf(in, a3.y, acc[13]);
        acc[14] = fmaf(in, a3.z, acc[14]); acc[15] = fmaf(in, a3.w, acc[15]);
      }
    }
  }
  __syncthreads();
#pragma unroll
  for (int c = 0; c < 16; ++c) {
    int co = cog * 16 + c;
    float v = fmaxf(fmaf(acc[c], wsc[WS_BN + 128 + co], wsc[WS_BN + 256 + co]), 0.f);
    pb[c * 256 + y * 16 + xx] = v;
  }
  __syncthreads();
  if (tid < 64) {
    int py = tid >> 3, px = tid & 7;
#pragma unroll
    for (int c = 0; c < 16; ++c) {
      const float* q = &pb[c * 256 + (2 * py) * 16 + 2 * px];
      float m = fmaxf(fmaxf(q[0], q[1]), fmaxf(q[16], q[17]));
      int co = cog * 16 + c;
      int fi = b * 8192 + co * 64 + py * 8 + px;
      p2f[fi] = m;
      out[32 + fi] = m;
    }
  }
}

// ---------------- k3b: fmax over f ----------------
__global__ __launch_bounds__(256) void k3b_fmax(const float* __restrict__ p2f,
                                                float* __restrict__ ws)
{
  int idx = blockIdx.x * 256 + threadIdx.x;   // 65536 float4s exactly
  float4 v = *(const float4*)(p2f + idx * 4);
  float m = fmaxf(fmaxf(v.x, v.y), fmaxf(v.z, v.w));
#pragma unroll
  for (int off = 32; off > 0; off >>= 1) m = fmaxf(m, __shfl_xor(m, off));
  if ((threadIdx.x & 63) == 0) atomicMax((int*)(ws + WS_FMAX), __float_as_int(m));
}

// ---------------- k3c: quantize f -> u8 ----------------
__global__ __launch_bounds__(256) void k3c_quant(const float* __restrict__ p2f,
                                                 const float* __restrict__ wsc,
                                                 unsigned* __restrict__ fq)
{
  int wid = blockIdx.x * 256 + threadIdx.x;   // 65536 words exactly
  float kq = 255.0f / wsc[WS_FMAX];
  float4 v = *(const float4*)(p2f + wid * 4);
  unsigned q0 = (unsigned)fmaf(v.x, kq, 0.5f);
  unsigned q1 = (unsigned)fmaf(v.y, kq, 0.5f);
  unsigned q2 = (unsigned)fmaf(v.z, kq, 0.5f);
  unsigned q3 = (unsigned)fmaf(v.w, kq, 0.5f);
  fq[wid] = q0 | (q1 << 8) | (q2 << 16) | (q3 << 24);
}

// ---------------- k4: L1-kNN via v_sad_u8 ----------------
// grid = (157 n-tiles of 128, 8 d-splits of 1024). 4 waves; wave w owns dims
// [s*1024+w*256, +256) in chunks of 32. Per-wave LDS: f [32 rows][32B] u8 (1KB),
// n [128 rows][48B stride] u8 (6KB). Thread tile 8b x 8n, 2 sad-words per step.
__global__ __launch_bounds__(256, 4) void k4_knn(
    const float* __restrict__ nbr, const unsigned* __restrict__ fq,
    const float* __restrict__ wsc, float* __restrict__ l1p)
{
  __shared__ __align__(16) char smem[28672];
  const int tid = threadIdx.x;
  const int w = tid >> 6, lane = tid & 63;
  const int b_thr = lane >> 4;    // 0..3
  const int n_thr = lane & 15;    // 0..15
  const int n0 = blockIdx.x * 128;
  const int s = blockIdx.y;
  const int dbase = s * 1024 + w * 256;
  char* ft = smem + w * 7168;
  char* nt = ft + 1024;
  const float kq = 255.0f / wsc[WS_FMAX];

  unsigned acc[8][8];
#pragma unroll
  for (int i = 0; i < 8; ++i)
#pragma unroll
    for (int j = 0; j < 8; ++j) acc[i][j] = 0u;

#pragma unroll 1
  for (int ch = 0; ch < 8; ++ch) {
    const int dc = dbase + ch * 32;
    __syncthreads();
    // stage f tile: 32 rows x 8 words (already u8)
#pragma unroll
    for (int t = 0; t < 4; ++t) {
      int uu = t * 64 + lane;
      int row = uu >> 3, wd = uu & 7;
      unsigned v = fq[row * 2048 + (dc >> 2) + wd];
      *(unsigned*)(ft + row * 32 + wd * 4) = v;
    }
    // stage n tile: 128 rows x 32 dims fp32 -> u8 quantize+pack
#pragma unroll
    for (int t = 0; t < 16; ++t) {
      int uu = t * 64 + lane;
      int row = uu >> 3, g = uu & 7;
      int nn = n0 + row; if (nn > 19999) nn = 19999;
      float4 v = *(const float4*)(nbr + (size_t)nn * 8192 + dc + g * 4);
      unsigned q0 = (unsigned)fmaf(v.x, kq, 0.5f);
      unsigned q1 = (unsigned)fmaf(v.y, kq, 0.5f);
      unsigned q2 = (unsigned)fmaf(v.z, kq, 0.5f);
      unsigned q3 = (unsigned)fmaf(v.w, kq, 0.5f);
      *(unsigned*)(nt + row * 48 + g * 4) = q0 | (q1 << 8) | (q2 << 16) | (q3 << 24);
    }
    __syncthreads();
#pragma unroll
    for (int h = 0; h < 4; ++h) {      // 8 dims (2 sad-words) per h
      uint2 fv[8], nv[8];
#pragma unroll
      for (int i = 0; i < 8; ++i)
        fv[i] = *(const uint2*)(ft + (b_thr + 4 * i) * 32 + h * 8);
#pragma unroll
      for (int j = 0; j < 8; ++j)
        nv[j] = *(const uint2*)(nt + (n_thr + 16 * j) * 48 + h * 8);
#pragma unroll
      for (int i = 0; i < 8; ++i)
#pragma unroll
        for (int j = 0; j < 8; ++j)
          acc[i][j] = sad4(fv[i].y, nv[j].y, sad4(fv[i].x, nv[j].x, acc[i][j]));
    }
  }

  // cross-wave reduce, 4 quarters of 8 b-rows (16 KB overlay)
  unsigned* red = (unsigned*)smem;
  __syncthreads();
#pragma unroll 1
  for (int qt = 0; qt < 4; ++qt) {
#pragma unroll
    for (int ii = 0; ii < 2; ++ii) {
      int i = qt * 2 + ii;
      int brow8 = ii * 4 + b_thr;
#pragma unroll
      for (int j = 0; j < 8; ++j)
        red[(brow8 * 128 + n_thr + 16 * j) * 4 + w] = acc[i][j];
    }
    __syncthreads();
#pragma unroll
    for (int k = 0; k < 4; ++k) {
      int e = k * 256 + tid;
      uint4 v = *(const uint4*)(red + e * 4);
      int brow = qt * 8 + (e >> 7), n = e & 127;
      l1p[(s * 32 + brow) * 20096 + n0 + n] = (float)(v.x + v.y + v.z + v.w);
    }
    __syncthreads();
  }
}

// ---------------- k5: reduce splits, exp-weight, mask, accumulate nr/dr ----------------
__global__ __launch_bounds__(256) void k5_red(
    const float* __restrict__ l1p, const int* __restrict__ labels,
    const float* __restrict__ wsc, float* __restrict__ nrdr)
{
  int b = blockIdx.y;
  int n = blockIdx.x * 256 + (int)threadIdx.x;
  int pred = ((const int*)(wsc + WS_PRED))[0];
  float c = wsc[WS_FMAX] * (-1.0f / (255.0f * 1000.0f));
  float wgt = 0.f, mk = 0.f;
  if (n < 20000) {
    float L1 = 0.f;
#pragma unroll
    for (int s2 = 0; s2 < 8; ++s2) L1 += l1p[(s2 * 32 + b) * 20096 + n];
    wgt = __expf(L1 * c);
    if (labels[n] == pred) mk = wgt;
  }
#pragma unroll
  for (int off = 32; off > 0; off >>= 1) {
    wgt += __shfl_xor(wgt, off);
    mk  += __shfl_xor(mk, off);
  }
  if ((threadIdx.x & 63) == 0) {
    atomicAdd(&nrdr[b], mk);
    atomicAdd(&nrdr[32 + b], wgt);
  }
}

// ---------------- k6: final ratio ----------------
__global__ void k6_out(const float* __restrict__ nrdr, float* __restrict__ out)
{
  int t = threadIdx.x;
  if (t < 32) out[t] = nrdr[t] / nrdr[32 + t];
}

extern "C" void kernel_launch(void* const* d_in, const int* in_sizes, int n_in,
                              void* d_out, int out_size, void* d_ws, size_t ws_size,
                              hipStream_t stream)
{
  (void)in_sizes; (void)n_in; (void)out_size; (void)ws_size;
  const float* x    = (const float*)d_in[0];
  const float* w1   = (const float*)d_in[1];
  const float* c1b  = (const float*)d_in[2];
  const float* g1   = (const float*)d_in[3];
  const float* be1  = (const float*)d_in[4];
  const float* m1   = (const float*)d_in[5];
  const float* v1   = (const float*)d_in[6];
  const float* w2   = (const float*)d_in[7];
  const float* c2b  = (const float*)d_in[8];
  const float* g2   = (const float*)d_in[9];
  const float* be2  = (const float*)d_in[10];
  const float* m2   = (const float*)d_in[11];
  const float* v2   = (const float*)d_in[12];
  const float* nbrf = (const float*)d_in[13];
  const int* labels = (const int*)d_in[14];
  float* ws = (float*)d_ws;
  float* out = (float*)d_out;

  k0a_init<<<1, 256, 0, stream>>>(c1b, g1, be1, m1, v1, c2b, g2, be2, m2, v2, ws);
  k0b_hist<<<20, 256, 0, stream>>>(labels, ws);
  k0c_mode<<<1, 64, 0, stream>>>(ws);
  k1_w2t<<<288, 256, 0, stream>>>(w2, ws + WS_W2T);
  k2_conv1<<<512, 256, 0, stream>>>(x, w1, ws, ws + WS_P1);
  k3_conv2<<<256, 256, 0, stream>>>(ws + WS_P1, ws + WS_W2T, ws, ws + WS_P2F, out);
  k3b_fmax<<<256, 256, 0, stream>>>(ws + WS_P2F, ws);
  k3c_quant<<<256, 256, 0, stream>>>(ws + WS_P2F, ws, (unsigned*)(ws + WS_FQ));
  k4_knn<<<dim3(157, 8), 256, 0, stream>>>(nbrf, (const unsigned*)(ws + WS_FQ), ws, ws + WS_L1P);
  k5_red<<<dim3(79, 32), 256, 0, stream>>>(ws + WS_L1P, labels, ws, ws + WS_NR);
  k6_out<<<1, 64, 0, stream>>>(ws + WS_NR, out);
}

// Round 6
// 685.813 us; speedup vs baseline: 1.0088x; 1.0039x over previous
//
#include <hip/hip_runtime.h>
#include <stdint.h>

// ---- workspace layout (float offsets) ----
#define WS_FQ    0u          // f quantized u8 [32][8192] = 65536 floats
#define WS_BN    65536u      // A1[64] B1[64] A2[128] B2[128]
#define WS_NR    65920u      // nr[32] dr[32]
#define WS_PRED  65984u      // int
#define WS_CNT   65985u      // int[10]
#define WS_FMAX  65995u      // float (atomicMax as int)
#define WS_X     66048u      // overlay region:
#define WS_P1    WS_X                  // conv: [32][64][16][16] = 524288
#define WS_W2T   (WS_X + 524288u)      // conv: [9][64][128]     = 73728
#define WS_P2F   (WS_X + 598016u)      // conv: [32][8192] f32   = 262144
#define WS_L1P   WS_X                  // knn:  [8][32][20096]   = 5144576

__device__ __forceinline__ unsigned sad4(unsigned a, unsigned b, unsigned c) {
#if __has_builtin(__builtin_amdgcn_sad_u8)
  return __builtin_amdgcn_sad_u8(a, b, c);
#else
  unsigned d;
  asm("v_sad_u8 %0, %1, %2, %3" : "=v"(d) : "v"(a), "v"(b), "v"(c));
  return d;
#endif
}

// ---------------- k0a: init + BN fold ----------------
__global__ __launch_bounds__(256) void k0a_init(
    const float* __restrict__ c1b, const float* __restrict__ g1,
    const float* __restrict__ be1, const float* __restrict__ m1,
    const float* __restrict__ v1,
    const float* __restrict__ c2b, const float* __restrict__ g2,
    const float* __restrict__ be2, const float* __restrict__ m2,
    const float* __restrict__ v2,
    float* __restrict__ ws)
{
  int tid = threadIdx.x;
  if (tid < 64) ws[WS_NR + tid] = 0.f;
  if (tid >= 192 && tid < 202) ((int*)(ws + WS_CNT))[tid - 192] = 0;
  if (tid == 202) ws[WS_FMAX] = 2.0f;
  if (tid < 64) {
    float A = g1[tid] * __frsqrt_rn(v1[tid] + 1e-5f);
    ws[WS_BN + tid] = A;
    ws[WS_BN + 64 + tid] = (c1b[tid] - m1[tid]) * A + be1[tid];
  } else if (tid < 192) {
    int c = tid - 64;
    float A = g2[c] * __frsqrt_rn(v2[c] + 1e-5f);
    ws[WS_BN + 128 + c] = A;
    ws[WS_BN + 256 + c] = (c2b[c] - m2[c]) * A + be2[c];
  }
}

// ---------------- k0b: label histogram (20 blocks) ----------------
__global__ __launch_bounds__(256) void k0b_hist(const int* __restrict__ labels,
                                                float* __restrict__ ws)
{
  __shared__ int cnt[10];
  int tid = threadIdx.x;
  if (tid < 10) cnt[tid] = 0;
  __syncthreads();
  int i0 = (blockIdx.x * 256 + tid) * 4;
  if (i0 + 3 < 20000) {
    int4 v = *(const int4*)(labels + i0);
    atomicAdd(&cnt[v.x], 1);
    atomicAdd(&cnt[v.y], 1);
    atomicAdd(&cnt[v.z], 1);
    atomicAdd(&cnt[v.w], 1);
  }
  __syncthreads();
  if (tid < 10) atomicAdd((int*)(ws + WS_CNT) + tid, cnt[tid]);
}

// ---------------- k0c: mode ----------------
__global__ void k0c_mode(float* __restrict__ ws)
{
  if (threadIdx.x == 0) {
    const int* cnt = (const int*)(ws + WS_CNT);
    int best = 0;
    for (int c = 1; c < 10; ++c) if (cnt[c] > cnt[best]) best = c;
    ((int*)(ws + WS_PRED))[0] = best;
  }
}

// ---------------- k1: transpose conv2 weights -> [kk][ci][co] ----------------
__global__ __launch_bounds__(256) void k1_w2t(const float* __restrict__ w2,
                                              float* __restrict__ w2t)
{
  int idx = blockIdx.x * 256 + threadIdx.x;
  if (idx >= 73728) return;
  int co = idx / 576, r = idx % 576, ci = r / 9, kk = r % 9;
  w2t[(kk * 64 + ci) * 128 + co] = w2[idx];
}

// ---------------- k2: conv1 + BN + ReLU + 2x2 maxpool (scalar weights) ----------------
__global__ __launch_bounds__(256) void k2_conv1(
    const float* __restrict__ x, const float* __restrict__ w1,
    const float* __restrict__ wsc, float* __restrict__ p1)
{
  __shared__ float xs[3 * 34 * 34];
  int tid = threadIdx.x;
  int b = blockIdx.x >> 4, cog = blockIdx.x & 15;

  for (int idx = tid; idx < 3 * 34 * 34; idx += 256) {
    int ci = idx / 1156, r = idx % 1156, yy = r / 34, xc = r % 34;
    int yg = yy - 1, xg = xc - 1;
    float v = 0.f;
    if ((unsigned)yg < 32u && (unsigned)xg < 32u)
      v = x[((b * 3 + ci) * 32 + yg) * 32 + xg];
    xs[idx] = v;
  }
  __syncthreads();

  int py = tid >> 4, px = tid & 15;
  float acc[4][4] = {};
#pragma unroll
  for (int ci = 0; ci < 3; ++ci)
#pragma unroll
    for (int ky = 0; ky < 3; ++ky)
#pragma unroll
      for (int kx = 0; kx < 3; ++kx) {
        const float* xp = &xs[ci * 1156 + (2 * py + ky) * 34 + (2 * px + kx)];
        float i00 = xp[0], i01 = xp[1], i10 = xp[34], i11 = xp[35];
#pragma unroll
        for (int c = 0; c < 4; ++c) {
          float wv = w1[cog * 108 + c * 27 + ci * 9 + ky * 3 + kx];  // uniform -> s_load
          acc[c][0] = fmaf(i00, wv, acc[c][0]);
          acc[c][1] = fmaf(i01, wv, acc[c][1]);
          acc[c][2] = fmaf(i10, wv, acc[c][2]);
          acc[c][3] = fmaf(i11, wv, acc[c][3]);
        }
      }
#pragma unroll
  for (int c = 0; c < 4; ++c) {
    int co = cog * 4 + c;
    float A = wsc[WS_BN + co], B = wsc[WS_BN + 64 + co];
    float v0 = fmaxf(fmaf(acc[c][0], A, B), 0.f);
    float v1 = fmaxf(fmaf(acc[c][1], A, B), 0.f);
    float v2 = fmaxf(fmaf(acc[c][2], A, B), 0.f);
    float v3 = fmaxf(fmaf(acc[c][3], A, B), 0.f);
    float m = fmaxf(fmaxf(v0, v1), fmaxf(v2, v3));
    p1[((b * 64 + co) * 16 + py) * 16 + px] = m;
  }
}

// ---------------- k3: conv2 + BN + ReLU + pool (scalar weights) ----------------
__global__ __launch_bounds__(256) void k3_conv2(
    const float* __restrict__ p1, const float* __restrict__ w2t,
    const float* __restrict__ wsc, float* __restrict__ p2f,
    float* __restrict__ out)
{
  __shared__ float in_s[32 * 324];  // 40.5 KB
  __shared__ float pb[4096];        // 16 KB pool buffer
  int tid = threadIdx.x;
  int b = blockIdx.x >> 3, cog = blockIdx.x & 7;
  int y = tid >> 4, xx = tid & 15;

  float acc[16];
#pragma unroll
  for (int c = 0; c < 16; ++c) acc[c] = 0.f;

  for (int h = 0; h < 2; ++h) {
    __syncthreads();
    for (int idx = tid; idx < 10368; idx += 256) {
      int ci = idx / 324, r = idx % 324, yy = r / 18, xc = r % 18;
      int yg = yy - 1, xg = xc - 1;
      float v = 0.f;
      if ((unsigned)yg < 16u && (unsigned)xg < 16u)
        v = p1[((b * 64 + h * 32 + ci) * 16 + yg) * 16 + xg];
      in_s[idx] = v;
    }
    __syncthreads();
    for (int ci = 0; ci < 32; ++ci) {
#pragma unroll
      for (int kk = 0; kk < 9; ++kk) {
        int ky = kk / 3, kx = kk % 3;
        float in = in_s[ci * 324 + (y + ky) * 18 + (xx + kx)];
        const float4* wp = (const float4*)(w2t + ((kk * 64 + h * 32 + ci) * 128 + cog * 16));
        float4 a0 = wp[0], a1 = wp[1], a2 = wp[2], a3 = wp[3];  // uniform -> s_load
        acc[0]  = fmaf(in, a0.x, acc[0]);  acc[1]  = fmaf(in, a0.y, acc[1]);
        acc[2]  = fmaf(in, a0.z, acc[2]);  acc[3]  = fmaf(in, a0.w, acc[3]);
        acc[4]  = fmaf(in, a1.x, acc[4]);  acc[5]  = fmaf(in, a1.y, acc[5]);
        acc[6]  = fmaf(in, a1.z, acc[6]);  acc[7]  = fmaf(in, a1.w, acc[7]);
        acc[8]  = fmaf(in, a2.x, acc[8]);  acc[9]  = fmaf(in, a2.y, acc[9]);
        acc[10] = fmaf(in, a2.z, acc[10]); acc[11] = fmaf(in, a2.w, acc[11]);
        acc[12] = fmaf(in, a3.x, acc[12]); acc[13] = fmaf(in, a3.y, acc[13]);
        acc[14] = fmaf(in, a3.z, acc[14]); acc[15] = fmaf(in, a3.w, acc[15]);
      }
    }
  }
  __syncthreads();
#pragma unroll
  for (int c = 0; c < 16; ++c) {
    int co = cog * 16 + c;
    float v = fmaxf(fmaf(acc[c], wsc[WS_BN + 128 + co], wsc[WS_BN + 256 + co]), 0.f);
    pb[c * 256 + y * 16 + xx] = v;
  }
  __syncthreads();
  if (tid < 64) {
    int py = tid >> 3, px = tid & 7;
#pragma unroll
    for (int c = 0; c < 16; ++c) {
      const float* q = &pb[c * 256 + (2 * py) * 16 + 2 * px];
      float m = fmaxf(fmaxf(q[0], q[1]), fmaxf(q[16], q[17]));
      int co = cog * 16 + c;
      int fi = b * 8192 + co * 64 + py * 8 + px;
      p2f[fi] = m;
      out[32 + fi] = m;
    }
  }
}

// ---------------- k3b: fmax over f ----------------
__global__ __launch_bounds__(256) void k3b_fmax(const float* __restrict__ p2f,
                                                float* __restrict__ ws)
{
  int idx = blockIdx.x * 256 + threadIdx.x;   // 65536 float4s exactly
  float4 v = *(const float4*)(p2f + idx * 4);
  float m = fmaxf(fmaxf(v.x, v.y), fmaxf(v.z, v.w));
#pragma unroll
  for (int off = 32; off > 0; off >>= 1) m = fmaxf(m, __shfl_xor(m, off));
  if ((threadIdx.x & 63) == 0) atomicMax((int*)(ws + WS_FMAX), __float_as_int(m));
}

// ---------------- k3c: quantize f -> u8 ----------------
__global__ __launch_bounds__(256) void k3c_quant(const float* __restrict__ p2f,
                                                 const float* __restrict__ wsc,
                                                 unsigned* __restrict__ fq)
{
  int wid = blockIdx.x * 256 + threadIdx.x;   // 65536 words exactly
  float kq = 255.0f / wsc[WS_FMAX];
  float4 v = *(const float4*)(p2f + wid * 4);
  unsigned q0 = (unsigned)fmaf(v.x, kq, 0.5f);
  unsigned q1 = (unsigned)fmaf(v.y, kq, 0.5f);
  unsigned q2 = (unsigned)fmaf(v.z, kq, 0.5f);
  unsigned q3 = (unsigned)fmaf(v.w, kq, 0.5f);
  fq[wid] = q0 | (q1 << 8) | (q2 << 16) | (q3 << 24);
}

// ---------------- k4: L1-kNN via v_sad_u8 ----------------
// grid = (157 n-tiles of 128, 8 d-splits of 1024). 4 waves; wave w owns dims
// [s*1024+w*256, +256) in chunks of 32. Per-wave LDS: f [32 rows][32B] u8 (1KB),
// n [128 rows][48B stride] u8 (6KB). Thread tile 8b x 8n, 2 sad-words per step.
__global__ __launch_bounds__(256, 4) void k4_knn(
    const float* __restrict__ nbr, const unsigned* __restrict__ fq,
    const float* __restrict__ wsc, float* __restrict__ l1p)
{
  __shared__ __align__(16) char smem[28672];
  const int tid = threadIdx.x;
  const int w = tid >> 6, lane = tid & 63;
  const int b_thr = lane >> 4;    // 0..3
  const int n_thr = lane & 15;    // 0..15
  const int n0 = blockIdx.x * 128;
  const int s = blockIdx.y;
  const int dbase = s * 1024 + w * 256;
  char* ft = smem + w * 7168;
  char* nt = ft + 1024;
  const float kq = 255.0f / wsc[WS_FMAX];

  unsigned acc[8][8];
#pragma unroll
  for (int i = 0; i < 8; ++i)
#pragma unroll
    for (int j = 0; j < 8; ++j) acc[i][j] = 0u;

#pragma unroll 1
  for (int ch = 0; ch < 8; ++ch) {
    const int dc = dbase + ch * 32;
    __syncthreads();
    // stage f tile: 32 rows x 8 words (already u8)
#pragma unroll
    for (int t = 0; t < 4; ++t) {
      int uu = t * 64 + lane;
      int row = uu >> 3, wd = uu & 7;
      unsigned v = fq[row * 2048 + (dc >> 2) + wd];
      *(unsigned*)(ft + row * 32 + wd * 4) = v;
    }
    // stage n tile: 128 rows x 32 dims fp32 -> u8 quantize+pack
#pragma unroll
    for (int t = 0; t < 16; ++t) {
      int uu = t * 64 + lane;
      int row = uu >> 3, g = uu & 7;
      int nn = n0 + row; if (nn > 19999) nn = 19999;
      float4 v = *(const float4*)(nbr + (size_t)nn * 8192 + dc + g * 4);
      unsigned q0 = (unsigned)fmaf(v.x, kq, 0.5f);
      unsigned q1 = (unsigned)fmaf(v.y, kq, 0.5f);
      unsigned q2 = (unsigned)fmaf(v.z, kq, 0.5f);
      unsigned q3 = (unsigned)fmaf(v.w, kq, 0.5f);
      *(unsigned*)(nt + row * 48 + g * 4) = q0 | (q1 << 8) | (q2 << 16) | (q3 << 24);
    }
    __syncthreads();
#pragma unroll
    for (int h = 0; h < 4; ++h) {      // 8 dims (2 sad-words) per h
      uint2 fv[8], nv[8];
#pragma unroll
      for (int i = 0; i < 8; ++i)
        fv[i] = *(const uint2*)(ft + (b_thr + 4 * i) * 32 + h * 8);
#pragma unroll
      for (int j = 0; j < 8; ++j)
        nv[j] = *(const uint2*)(nt + (n_thr + 16 * j) * 48 + h * 8);
#pragma unroll
      for (int i = 0; i < 8; ++i)
#pragma unroll
        for (int j = 0; j < 8; ++j)
          acc[i][j] = sad4(fv[i].y, nv[j].y, sad4(fv[i].x, nv[j].x, acc[i][j]));
    }
  }

  // cross-wave reduce, 4 quarters of 8 b-rows (16 KB overlay)
  unsigned* red = (unsigned*)smem;
  __syncthreads();
#pragma unroll 1
  for (int qt = 0; qt < 4; ++qt) {
#pragma unroll
    for (int ii = 0; ii < 2; ++ii) {
      int i = qt * 2 + ii;
      int brow8 = ii * 4 + b_thr;
#pragma unroll
      for (int j = 0; j < 8; ++j)
        red[(brow8 * 128 + n_thr + 16 * j) * 4 + w] = acc[i][j];
    }
    __syncthreads();
#pragma unroll
    for (int k = 0; k < 4; ++k) {
      int e = k * 256 + tid;
      uint4 v = *(const uint4*)(red + e * 4);
      int brow = qt * 8 + (e >> 7), n = e & 127;
      l1p[(s * 32 + brow) * 20096 + n0 + n] = (float)(v.x + v.y + v.z + v.w);
    }
    __syncthreads();
  }
}

// ---------------- k5: reduce splits, exp-weight, mask, accumulate nr/dr ----------------
__global__ __launch_bounds__(256) void k5_red(
    const float* __restrict__ l1p, const int* __restrict__ labels,
    const float* __restrict__ wsc, float* __restrict__ nrdr)
{
  int b = blockIdx.y;
  int n = blockIdx.x * 256 + (int)threadIdx.x;
  int pred = ((const int*)(wsc + WS_PRED))[0];
  float c = wsc[WS_FMAX] * (-1.0f / (255.0f * 1000.0f));
  float wgt = 0.f, mk = 0.f;
  if (n < 20000) {
    float L1 = 0.f;
#pragma unroll
    for (int s2 = 0; s2 < 8; ++s2) L1 += l1p[(s2 * 32 + b) * 20096 + n];
    wgt = __expf(L1 * c);
    if (labels[n] == pred) mk = wgt;
  }
#pragma unroll
  for (int off = 32; off > 0; off >>= 1) {
    wgt += __shfl_xor(wgt, off);
    mk  += __shfl_xor(mk, off);
  }
  if ((threadIdx.x & 63) == 0) {
    atomicAdd(&nrdr[b], mk);
    atomicAdd(&nrdr[32 + b], wgt);
  }
}

// ---------------- k6: final ratio ----------------
__global__ void k6_out(const float* __restrict__ nrdr, float* __restrict__ out)
{
  int t = threadIdx.x;
  if (t < 32) out[t] = nrdr[t] / nrdr[32 + t];
}

extern "C" void kernel_launch(void* const* d_in, const int* in_sizes, int n_in,
                              void* d_out, int out_size, void* d_ws, size_t ws_size,
                              hipStream_t stream)
{
  (void)in_sizes; (void)n_in; (void)out_size; (void)ws_size;
  const float* x    = (const float*)d_in[0];
  const float* w1   = (const float*)d_in[1];
  const float* c1b  = (const float*)d_in[2];
  const float* g1   = (const float*)d_in[3];
  const float* be1  = (const float*)d_in[4];
  const float* m1   = (const float*)d_in[5];
  const float* v1   = (const float*)d_in[6];
  const float* w2   = (const float*)d_in[7];
  const float* c2b  = (const float*)d_in[8];
  const float* g2   = (const float*)d_in[9];
  const float* be2  = (const float*)d_in[10];
  const float* m2   = (const float*)d_in[11];
  const float* v2   = (const float*)d_in[12];
  const float* nbrf = (const float*)d_in[13];
  const int* labels = (const int*)d_in[14];
  float* ws = (float*)d_ws;
  float* out = (float*)d_out;

  k0a_init<<<1, 256, 0, stream>>>(c1b, g1, be1, m1, v1, c2b, g2, be2, m2, v2, ws);
  k0b_hist<<<20, 256, 0, stream>>>(labels, ws);
  k0c_mode<<<1, 64, 0, stream>>>(ws);
  k1_w2t<<<288, 256, 0, stream>>>(w2, ws + WS_W2T);
  k2_conv1<<<512, 256, 0, stream>>>(x, w1, ws, ws + WS_P1);
  k3_conv2<<<256, 256, 0, stream>>>(ws + WS_P1, ws + WS_W2T, ws, ws + WS_P2F, out);
  k3b_fmax<<<256, 256, 0, stream>>>(ws + WS_P2F, ws);
  k3c_quant<<<256, 256, 0, stream>>>(ws + WS_P2F, ws, (unsigned*)(ws + WS_FQ));
  k4_knn<<<dim3(157, 8), 256, 0, stream>>>(nbrf, (const unsigned*)(ws + WS_FQ), ws, ws + WS_L1P);
  k5_red<<<dim3(79, 32), 256, 0, stream>>>(ws + WS_L1P, labels, ws, ws + WS_NR);
  k6_out<<<1, 64, 0, stream>>>(ws + WS_NR, out);
}

// Round 7
// 684.908 us; speedup vs baseline: 1.0101x; 1.0013x over previous
//
#include <hip/hip_runtime.h>
#include <stdint.h>

// ---- workspace layout (float offsets) ----
#define WS_FQ    0u          // f quantized u8 [32][8192] = 65536 floats
#define WS_BN    65536u      // A1[64] B1[64] A2[128] B2[128]
#define WS_NR    65920u      // nr[32] dr[32]
#define WS_PRED  65984u      // int
#define WS_CNT   65985u      // int[10]
#define WS_FMAX  65995u      // float (atomicMax as int)
#define WS_X     66048u      // overlay region:
#define WS_P1    WS_X                  // conv: [32][64][16][16] = 524288
#define WS_W2T   (WS_X + 524288u)      // conv: [9][64][128]     = 73728
#define WS_P2F   (WS_X + 598016u)      // conv: [32][8192] f32   = 262144
#define WS_L1P   WS_X                  // knn:  [8][32][20096]   = 5144576

__device__ __forceinline__ unsigned sad4(unsigned a, unsigned b, unsigned c) {
#if __has_builtin(__builtin_amdgcn_sad_u8)
  return __builtin_amdgcn_sad_u8(a, b, c);
#else
  unsigned d;
  asm("v_sad_u8 %0, %1, %2, %3" : "=v"(d) : "v"(a), "v"(b), "v"(c));
  return d;
#endif
}

// ---------------- k0a: init + BN fold ----------------
__global__ __launch_bounds__(256) void k0a_init(
    const float* __restrict__ c1b, const float* __restrict__ g1,
    const float* __restrict__ be1, const float* __restrict__ m1,
    const float* __restrict__ v1,
    const float* __restrict__ c2b, const float* __restrict__ g2,
    const float* __restrict__ be2, const float* __restrict__ m2,
    const float* __restrict__ v2,
    float* __restrict__ ws)
{
  int tid = threadIdx.x;
  if (tid < 64) ws[WS_NR + tid] = 0.f;
  if (tid >= 192 && tid < 202) ((int*)(ws + WS_CNT))[tid - 192] = 0;
  if (tid == 202) ws[WS_FMAX] = 2.0f;
  if (tid < 64) {
    float A = g1[tid] * __frsqrt_rn(v1[tid] + 1e-5f);
    ws[WS_BN + tid] = A;
    ws[WS_BN + 64 + tid] = (c1b[tid] - m1[tid]) * A + be1[tid];
  } else if (tid < 192) {
    int c = tid - 64;
    float A = g2[c] * __frsqrt_rn(v2[c] + 1e-5f);
    ws[WS_BN + 128 + c] = A;
    ws[WS_BN + 256 + c] = (c2b[c] - m2[c]) * A + be2[c];
  }
}

// ---------------- k0b: label histogram (20 blocks) ----------------
__global__ __launch_bounds__(256) void k0b_hist(const int* __restrict__ labels,
                                                float* __restrict__ ws)
{
  __shared__ int cnt[10];
  int tid = threadIdx.x;
  if (tid < 10) cnt[tid] = 0;
  __syncthreads();
  int i0 = (blockIdx.x * 256 + tid) * 4;
  if (i0 + 3 < 20000) {
    int4 v = *(const int4*)(labels + i0);
    atomicAdd(&cnt[v.x], 1);
    atomicAdd(&cnt[v.y], 1);
    atomicAdd(&cnt[v.z], 1);
    atomicAdd(&cnt[v.w], 1);
  }
  __syncthreads();
  if (tid < 10) atomicAdd((int*)(ws + WS_CNT) + tid, cnt[tid]);
}

// ---------------- k0c: mode ----------------
__global__ void k0c_mode(float* __restrict__ ws)
{
  if (threadIdx.x == 0) {
    const int* cnt = (const int*)(ws + WS_CNT);
    int best = 0;
    for (int c = 1; c < 10; ++c) if (cnt[c] > cnt[best]) best = c;
    ((int*)(ws + WS_PRED))[0] = best;
  }
}

// ---------------- k1: transpose conv2 weights -> [kk][ci][co] ----------------
__global__ __launch_bounds__(256) void k1_w2t(const float* __restrict__ w2,
                                              float* __restrict__ w2t)
{
  int idx = blockIdx.x * 256 + threadIdx.x;
  if (idx >= 73728) return;
  int co = idx / 576, r = idx % 576, ci = r / 9, kk = r % 9;
  w2t[(kk * 64 + ci) * 128 + co] = w2[idx];
}

// ---------------- k2: conv1 + BN + ReLU + 2x2 maxpool (scalar weights) ----------------
__global__ __launch_bounds__(256) void k2_conv1(
    const float* __restrict__ x, const float* __restrict__ w1,
    const float* __restrict__ wsc, float* __restrict__ p1)
{
  __shared__ float xs[3 * 34 * 34];
  int tid = threadIdx.x;
  int b = blockIdx.x >> 4, cog = blockIdx.x & 15;

  for (int idx = tid; idx < 3 * 34 * 34; idx += 256) {
    int ci = idx / 1156, r = idx % 1156, yy = r / 34, xc = r % 34;
    int yg = yy - 1, xg = xc - 1;
    float v = 0.f;
    if ((unsigned)yg < 32u && (unsigned)xg < 32u)
      v = x[((b * 3 + ci) * 32 + yg) * 32 + xg];
    xs[idx] = v;
  }
  __syncthreads();

  int py = tid >> 4, px = tid & 15;
  float acc[4][4] = {};
#pragma unroll
  for (int ci = 0; ci < 3; ++ci)
#pragma unroll
    for (int ky = 0; ky < 3; ++ky)
#pragma unroll
      for (int kx = 0; kx < 3; ++kx) {
        const float* xp = &xs[ci * 1156 + (2 * py + ky) * 34 + (2 * px + kx)];
        float i00 = xp[0], i01 = xp[1], i10 = xp[34], i11 = xp[35];
#pragma unroll
        for (int c = 0; c < 4; ++c) {
          float wv = w1[cog * 108 + c * 27 + ci * 9 + ky * 3 + kx];  // uniform -> s_load
          acc[c][0] = fmaf(i00, wv, acc[c][0]);
          acc[c][1] = fmaf(i01, wv, acc[c][1]);
          acc[c][2] = fmaf(i10, wv, acc[c][2]);
          acc[c][3] = fmaf(i11, wv, acc[c][3]);
        }
      }
#pragma unroll
  for (int c = 0; c < 4; ++c) {
    int co = cog * 4 + c;
    float A = wsc[WS_BN + co], B = wsc[WS_BN + 64 + co];
    float v0 = fmaxf(fmaf(acc[c][0], A, B), 0.f);
    float v1 = fmaxf(fmaf(acc[c][1], A, B), 0.f);
    float v2 = fmaxf(fmaf(acc[c][2], A, B), 0.f);
    float v3 = fmaxf(fmaf(acc[c][3], A, B), 0.f);
    float m = fmaxf(fmaxf(v0, v1), fmaxf(v2, v3));
    p1[((b * 64 + co) * 16 + py) * 16 + px] = m;
  }
}

// ---------------- k3: conv2 + BN + ReLU + pool (scalar weights) ----------------
__global__ __launch_bounds__(256) void k3_conv2(
    const float* __restrict__ p1, const float* __restrict__ w2t,
    const float* __restrict__ wsc, float* __restrict__ p2f,
    float* __restrict__ out)
{
  __shared__ float in_s[32 * 324];  // 40.5 KB
  __shared__ float pb[4096];        // 16 KB pool buffer
  int tid = threadIdx.x;
  int b = blockIdx.x >> 3, cog = blockIdx.x & 7;
  int y = tid >> 4, xx = tid & 15;

  float acc[16];
#pragma unroll
  for (int c = 0; c < 16; ++c) acc[c] = 0.f;

  for (int h = 0; h < 2; ++h) {
    __syncthreads();
    for (int idx = tid; idx < 10368; idx += 256) {
      int ci = idx / 324, r = idx % 324, yy = r / 18, xc = r % 18;
      int yg = yy - 1, xg = xc - 1;
      float v = 0.f;
      if ((unsigned)yg < 16u && (unsigned)xg < 16u)
        v = p1[((b * 64 + h * 32 + ci) * 16 + yg) * 16 + xg];
      in_s[idx] = v;
    }
    __syncthreads();
    for (int ci = 0; ci < 32; ++ci) {
#pragma unroll
      for (int kk = 0; kk < 9; ++kk) {
        int ky = kk / 3, kx = kk % 3;
        float in = in_s[ci * 324 + (y + ky) * 18 + (xx + kx)];
        const float4* wp = (const float4*)(w2t + ((kk * 64 + h * 32 + ci) * 128 + cog * 16));
        float4 a0 = wp[0], a1 = wp[1], a2 = wp[2], a3 = wp[3];  // uniform -> s_load
        acc[0]  = fmaf(in, a0.x, acc[0]);  acc[1]  = fmaf(in, a0.y, acc[1]);
        acc[2]  = fmaf(in, a0.z, acc[2]);  acc[3]  = fmaf(in, a0.w, acc[3]);
        acc[4]  = fmaf(in, a1.x, acc[4]);  acc[5]  = fmaf(in, a1.y, acc[5]);
        acc[6]  = fmaf(in, a1.z, acc[6]);  acc[7]  = fmaf(in, a1.w, acc[7]);
        acc[8]  = fmaf(in, a2.x, acc[8]);  acc[9]  = fmaf(in, a2.y, acc[9]);
        acc[10] = fmaf(in, a2.z, acc[10]); acc[11] = fmaf(in, a2.w, acc[11]);
        acc[12] = fmaf(in, a3.x, acc[12]); acc[13] = fmaf(in, a3.y, acc[13]);
        acc[14] = fmaf(in, a3.z, acc[14]); acc[15] = fmaf(in, a3.w, acc[15]);
      }
    }
  }
  __syncthreads();
#pragma unroll
  for (int c = 0; c < 16; ++c) {
    int co = cog * 16 + c;
    float v = fmaxf(fmaf(acc[c], wsc[WS_BN + 128 + co], wsc[WS_BN + 256 + co]), 0.f);
    pb[c * 256 + y * 16 + xx] = v;
  }
  __syncthreads();
  if (tid < 64) {
    int py = tid >> 3, px = tid & 7;
#pragma unroll
    for (int c = 0; c < 16; ++c) {
      const float* q = &pb[c * 256 + (2 * py) * 16 + 2 * px];
      float m = fmaxf(fmaxf(q[0], q[1]), fmaxf(q[16], q[17]));
      int co = cog * 16 + c;
      int fi = b * 8192 + co * 64 + py * 8 + px;
      p2f[fi] = m;
      out[32 + fi] = m;
    }
  }
}

// ---------------- k3b: fmax over f ----------------
__global__ __launch_bounds__(256) void k3b_fmax(const float* __restrict__ p2f,
                                                float* __restrict__ ws)
{
  int idx = blockIdx.x * 256 + threadIdx.x;   // 65536 float4s exactly
  float4 v = *(const float4*)(p2f + idx * 4);
  float m = fmaxf(fmaxf(v.x, v.y), fmaxf(v.z, v.w));
#pragma unroll
  for (int off = 32; off > 0; off >>= 1) m = fmaxf(m, __shfl_xor(m, off));
  if ((threadIdx.x & 63) == 0) atomicMax((int*)(ws + WS_FMAX), __float_as_int(m));
}

// ---------------- k3c: quantize f -> u8 ----------------
__global__ __launch_bounds__(256) void k3c_quant(const float* __restrict__ p2f,
                                                 const float* __restrict__ wsc,
                                                 unsigned* __restrict__ fq)
{
  int wid = blockIdx.x * 256 + threadIdx.x;   // 65536 words exactly
  float kq = 255.0f / wsc[WS_FMAX];
  float4 v = *(const float4*)(p2f + wid * 4);
  unsigned q0 = (unsigned)fmaf(v.x, kq, 0.5f);
  unsigned q1 = (unsigned)fmaf(v.y, kq, 0.5f);
  unsigned q2 = (unsigned)fmaf(v.z, kq, 0.5f);
  unsigned q3 = (unsigned)fmaf(v.w, kq, 0.5f);
  fq[wid] = q0 | (q1 << 8) | (q2 << 16) | (q3 << 24);
}

// ---------------- k4: L1-kNN via v_sad_u8 ----------------
// grid = (157 n-tiles of 128, 8 d-splits of 1024). 4 waves; wave w owns dims
// [s*1024+w*256, +256) in chunks of 32. Per-wave LDS: f [32 rows][32B] u8 (1KB),
// n [128 rows][48B stride] u8 (6KB). Thread tile 8b x 8n, 2 sad-words per step.
__global__ __launch_bounds__(256, 4) void k4_knn(
    const float* __restrict__ nbr, const unsigned* __restrict__ fq,
    const float* __restrict__ wsc, float* __restrict__ l1p)
{
  __shared__ __align__(16) char smem[28672];
  const int tid = threadIdx.x;
  const int w = tid >> 6, lane = tid & 63;
  const int b_thr = lane >> 4;    // 0..3
  const int n_thr = lane & 15;    // 0..15
  const int n0 = blockIdx.x * 128;
  const int s = blockIdx.y;
  const int dbase = s * 1024 + w * 256;
  char* ft = smem + w * 7168;
  char* nt = ft + 1024;
  const float kq = 255.0f / wsc[WS_FMAX];

  unsigned acc[8][8];
#pragma unroll
  for (int i = 0; i < 8; ++i)
#pragma unroll
    for (int j = 0; j < 8; ++j) acc[i][j] = 0u;

#pragma unroll 1
  for (int ch = 0; ch < 8; ++ch) {
    const int dc = dbase + ch * 32;
    __syncthreads();
    // stage f tile: 32 rows x 8 words (already u8)
#pragma unroll
    for (int t = 0; t < 4; ++t) {
      int uu = t * 64 + lane;
      int row = uu >> 3, wd = uu & 7;
      unsigned v = fq[row * 2048 + (dc >> 2) + wd];
      *(unsigned*)(ft + row * 32 + wd * 4) = v;
    }
    // stage n tile: 128 rows x 32 dims fp32 -> u8 quantize+pack
#pragma unroll
    for (int t = 0; t < 16; ++t) {
      int uu = t * 64 + lane;
      int row = uu >> 3, g = uu & 7;
      int nn = n0 + row; if (nn > 19999) nn = 19999;
      float4 v = *(const float4*)(nbr + (size_t)nn * 8192 + dc + g * 4);
      unsigned q0 = (unsigned)fmaf(v.x, kq, 0.5f);
      unsigned q1 = (unsigned)fmaf(v.y, kq, 0.5f);
      unsigned q2 = (unsigned)fmaf(v.z, kq, 0.5f);
      unsigned q3 = (unsigned)fmaf(v.w, kq, 0.5f);
      *(unsigned*)(nt + row * 48 + g * 4) = q0 | (q1 << 8) | (q2 << 16) | (q3 << 24);
    }
    __syncthreads();
#pragma unroll
    for (int h = 0; h < 4; ++h) {      // 8 dims (2 sad-words) per h
      uint2 fv[8], nv[8];
#pragma unroll
      for (int i = 0; i < 8; ++i)
        fv[i] = *(const uint2*)(ft + (b_thr + 4 * i) * 32 + h * 8);
#pragma unroll
      for (int j = 0; j < 8; ++j)
        nv[j] = *(const uint2*)(nt + (n_thr + 16 * j) * 48 + h * 8);
#pragma unroll
      for (int i = 0; i < 8; ++i)
#pragma unroll
        for (int j = 0; j < 8; ++j)
          acc[i][j] = sad4(fv[i].y, nv[j].y, sad4(fv[i].x, nv[j].x, acc[i][j]));
    }
  }

  // cross-wave reduce, 4 quarters of 8 b-rows (16 KB overlay)
  unsigned* red = (unsigned*)smem;
  __syncthreads();
#pragma unroll 1
  for (int qt = 0; qt < 4; ++qt) {
#pragma unroll
    for (int ii = 0; ii < 2; ++ii) {
      int i = qt * 2 + ii;
      int brow8 = ii * 4 + b_thr;
#pragma unroll
      for (int j = 0; j < 8; ++j)
        red[(brow8 * 128 + n_thr + 16 * j) * 4 + w] = acc[i][j];
    }
    __syncthreads();
#pragma unroll
    for (int k = 0; k < 4; ++k) {
      int e = k * 256 + tid;
      uint4 v = *(const uint4*)(red + e * 4);
      int brow = qt * 8 + (e >> 7), n = e & 127;
      l1p[(s * 32 + brow) * 20096 + n0 + n] = (float)(v.x + v.y + v.z + v.w);
    }
    __syncthreads();
  }
}

// ---------------- k5: reduce splits, exp-weight, mask, accumulate nr/dr ----------------
__global__ __launch_bounds__(256) void k5_red(
    const float* __restrict__ l1p, const int* __restrict__ labels,
    const float* __restrict__ wsc, float* __restrict__ nrdr)
{
  int b = blockIdx.y;
  int n = blockIdx.x * 256 + (int)threadIdx.x;
  int pred = ((const int*)(wsc + WS_PRED))[0];
  float c = wsc[WS_FMAX] * (-1.0f / (255.0f * 1000.0f));
  float wgt = 0.f, mk = 0.f;
  if (n < 20000) {
    float L1 = 0.f;
#pragma unroll
    for (int s2 = 0; s2 < 8; ++s2) L1 += l1p[(s2 * 32 + b) * 20096 + n];
    wgt = __expf(L1 * c);
    if (labels[n] == pred) mk = wgt;
  }
#pragma unroll
  for (int off = 32; off > 0; off >>= 1) {
    wgt += __shfl_xor(wgt, off);
    mk  += __shfl_xor(mk, off);
  }
  if ((threadIdx.x & 63) == 0) {
    atomicAdd(&nrdr[b], mk);
    atomicAdd(&nrdr[32 + b], wgt);
  }
}

// ---------------- k6: final ratio ----------------
__global__ void k6_out(const float* __restrict__ nrdr, float* __restrict__ out)
{
  int t = threadIdx.x;
  if (t < 32) out[t] = nrdr[t] / nrdr[32 + t];
}

extern "C" void kernel_launch(void* const* d_in, const int* in_sizes, int n_in,
                              void* d_out, int out_size, void* d_ws, size_t ws_size,
                              hipStream_t stream)
{
  (void)in_sizes; (void)n_in; (void)out_size; (void)ws_size;
  const float* x    = (const float*)d_in[0];
  const float* w1   = (const float*)d_in[1];
  const float* c1b  = (const float*)d_in[2];
  const float* g1   = (const float*)d_in[3];
  const float* be1  = (const float*)d_in[4];
  const float* m1   = (const float*)d_in[5];
  const float* v1   = (const float*)d_in[6];
  const float* w2   = (const float*)d_in[7];
  const float* c2b  = (const float*)d_in[8];
  const float* g2   = (const float*)d_in[9];
  const float* be2  = (const float*)d_in[10];
  const float* m2   = (const float*)d_in[11];
  const float* v2   = (const float*)d_in[12];
  const float* nbrf = (const float*)d_in[13];
  const int* labels = (const int*)d_in[14];
  float* ws = (float*)d_ws;
  float* out = (float*)d_out;

  k0a_init<<<1, 256, 0, stream>>>(c1b, g1, be1, m1, v1, c2b, g2, be2, m2, v2, ws);
  k0b_hist<<<20, 256, 0, stream>>>(labels, ws);
  k0c_mode<<<1, 64, 0, stream>>>(ws);
  k1_w2t<<<288, 256, 0, stream>>>(w2, ws + WS_W2T);
  k2_conv1<<<512, 256, 0, stream>>>(x, w1, ws, ws + WS_P1);
  k3_conv2<<<256, 256, 0, stream>>>(ws + WS_P1, ws + WS_W2T, ws, ws + WS_P2F, out);
  k3b_fmax<<<256, 256, 0, stream>>>(ws + WS_P2F, ws);
  k3c_quant<<<256, 256, 0, stream>>>(ws + WS_P2F, ws, (unsigned*)(ws + WS_FQ));
  k4_knn<<<dim3(157, 8), 256, 0, stream>>>(nbrf, (const unsigned*)(ws + WS_FQ), ws, ws + WS_L1P);
  k5_red<<<dim3(79, 32), 256, 0, stream>>>(ws + WS_L1P, labels, ws, ws + WS_NR);
  k6_out<<<1, 64, 0, stream>>>(ws + WS_NR, out);
}

// Round 8
// 488.809 us; speedup vs baseline: 1.4153x; 1.4012x over previous
//
#include <hip/hip_runtime.h>
#include <stdint.h>

// ---- workspace layout (float offsets) ----
#define WS_FQ    0u          // f quantized u8 [32][8192] = 65536 floats
#define WS_BN    65536u      // A1[64] B1[64] A2[128] B2[128]
#define WS_NR    65920u      // nr[32] dr[32]
#define WS_PRED  65984u      // int
#define WS_CNT   65985u      // int[10]
#define WS_FMAX  65995u      // float (atomicMax as int)
#define WS_X     66048u      // overlay region:
#define WS_P1    WS_X                  // conv: [32][64][16][16] = 524288
#define WS_W2T   (WS_X + 524288u)      // conv: [9][64][128]     = 73728
#define WS_P2F   (WS_X + 598016u)      // conv: [32][8192] f32   = 262144
#define WS_L1P   WS_X                  // knn:  [8][32][20096]   = 5144576

__device__ __forceinline__ unsigned sad4(unsigned a, unsigned b, unsigned c) {
#if __has_builtin(__builtin_amdgcn_sad_u8)
  return __builtin_amdgcn_sad_u8(a, b, c);
#else
  unsigned d;
  asm("v_sad_u8 %0, %1, %2, %3" : "=v"(d) : "v"(a), "v"(b), "v"(c));
  return d;
#endif
}

// ---------------- k0a: init + BN fold ----------------
__global__ __launch_bounds__(256) void k0a_init(
    const float* __restrict__ c1b, const float* __restrict__ g1,
    const float* __restrict__ be1, const float* __restrict__ m1,
    const float* __restrict__ v1,
    const float* __restrict__ c2b, const float* __restrict__ g2,
    const float* __restrict__ be2, const float* __restrict__ m2,
    const float* __restrict__ v2,
    float* __restrict__ ws)
{
  int tid = threadIdx.x;
  if (tid < 64) ws[WS_NR + tid] = 0.f;
  if (tid >= 192 && tid < 202) ((int*)(ws + WS_CNT))[tid - 192] = 0;
  if (tid == 202) ws[WS_FMAX] = 2.0f;
  if (tid < 64) {
    float A = g1[tid] * __frsqrt_rn(v1[tid] + 1e-5f);
    ws[WS_BN + tid] = A;
    ws[WS_BN + 64 + tid] = (c1b[tid] - m1[tid]) * A + be1[tid];
  } else if (tid < 192) {
    int c = tid - 64;
    float A = g2[c] * __frsqrt_rn(v2[c] + 1e-5f);
    ws[WS_BN + 128 + c] = A;
    ws[WS_BN + 256 + c] = (c2b[c] - m2[c]) * A + be2[c];
  }
}

// ---------------- k0b: label histogram (20 blocks) ----------------
__global__ __launch_bounds__(256) void k0b_hist(const int* __restrict__ labels,
                                                float* __restrict__ ws)
{
  __shared__ int cnt[10];
  int tid = threadIdx.x;
  if (tid < 10) cnt[tid] = 0;
  __syncthreads();
  int i0 = (blockIdx.x * 256 + tid) * 4;
  if (i0 + 3 < 20000) {
    int4 v = *(const int4*)(labels + i0);
    atomicAdd(&cnt[v.x], 1);
    atomicAdd(&cnt[v.y], 1);
    atomicAdd(&cnt[v.z], 1);
    atomicAdd(&cnt[v.w], 1);
  }
  __syncthreads();
  if (tid < 10) atomicAdd((int*)(ws + WS_CNT) + tid, cnt[tid]);
}

// ---------------- k0c: mode ----------------
__global__ void k0c_mode(float* __restrict__ ws)
{
  if (threadIdx.x == 0) {
    const int* cnt = (const int*)(ws + WS_CNT);
    int best = 0;
    for (int c = 1; c < 10; ++c) if (cnt[c] > cnt[best]) best = c;
    ((int*)(ws + WS_PRED))[0] = best;
  }
}

// ---------------- k1: transpose conv2 weights -> [kk][ci][co] ----------------
__global__ __launch_bounds__(256) void k1_w2t(const float* __restrict__ w2,
                                              float* __restrict__ w2t)
{
  int idx = blockIdx.x * 256 + threadIdx.x;
  if (idx >= 73728) return;
  int co = idx / 576, r = idx % 576, ci = r / 9, kk = r % 9;
  w2t[(kk * 64 + ci) * 128 + co] = w2[idx];
}

// ---------------- k2: conv1 + BN + ReLU + 2x2 maxpool (scalar weights) ----------------
__global__ __launch_bounds__(256) void k2_conv1(
    const float* __restrict__ x, const float* __restrict__ w1,
    const float* __restrict__ wsc, float* __restrict__ p1)
{
  __shared__ float xs[3 * 34 * 34];
  int tid = threadIdx.x;
  int b = blockIdx.x >> 4, cog = blockIdx.x & 15;

  for (int idx = tid; idx < 3 * 34 * 34; idx += 256) {
    int ci = idx / 1156, r = idx % 1156, yy = r / 34, xc = r % 34;
    int yg = yy - 1, xg = xc - 1;
    float v = 0.f;
    if ((unsigned)yg < 32u && (unsigned)xg < 32u)
      v = x[((b * 3 + ci) * 32 + yg) * 32 + xg];
    xs[idx] = v;
  }
  __syncthreads();

  int py = tid >> 4, px = tid & 15;
  float acc[4][4] = {};
#pragma unroll
  for (int ci = 0; ci < 3; ++ci)
#pragma unroll
    for (int ky = 0; ky < 3; ++ky)
#pragma unroll
      for (int kx = 0; kx < 3; ++kx) {
        const float* xp = &xs[ci * 1156 + (2 * py + ky) * 34 + (2 * px + kx)];
        float i00 = xp[0], i01 = xp[1], i10 = xp[34], i11 = xp[35];
#pragma unroll
        for (int c = 0; c < 4; ++c) {
          float wv = w1[cog * 108 + c * 27 + ci * 9 + ky * 3 + kx];  // uniform -> s_load
          acc[c][0] = fmaf(i00, wv, acc[c][0]);
          acc[c][1] = fmaf(i01, wv, acc[c][1]);
          acc[c][2] = fmaf(i10, wv, acc[c][2]);
          acc[c][3] = fmaf(i11, wv, acc[c][3]);
        }
      }
#pragma unroll
  for (int c = 0; c < 4; ++c) {
    int co = cog * 4 + c;
    float A = wsc[WS_BN + co], B = wsc[WS_BN + 64 + co];
    float v0 = fmaxf(fmaf(acc[c][0], A, B), 0.f);
    float v1 = fmaxf(fmaf(acc[c][1], A, B), 0.f);
    float v2 = fmaxf(fmaf(acc[c][2], A, B), 0.f);
    float v3 = fmaxf(fmaf(acc[c][3], A, B), 0.f);
    float m = fmaxf(fmaxf(v0, v1), fmaxf(v2, v3));
    p1[((b * 64 + co) * 16 + py) * 16 + px] = m;
  }
}

// ---------------- k3: conv2 + BN + ReLU + pool (scalar weights) ----------------
__global__ __launch_bounds__(256) void k3_conv2(
    const float* __restrict__ p1, const float* __restrict__ w2t,
    const float* __restrict__ wsc, float* __restrict__ p2f,
    float* __restrict__ out)
{
  __shared__ float in_s[32 * 324];  // 40.5 KB
  __shared__ float pb[4096];        // 16 KB pool buffer
  int tid = threadIdx.x;
  int b = blockIdx.x >> 3, cog = blockIdx.x & 7;
  int y = tid >> 4, xx = tid & 15;

  float acc[16];
#pragma unroll
  for (int c = 0; c < 16; ++c) acc[c] = 0.f;

  for (int h = 0; h < 2; ++h) {
    __syncthreads();
    for (int idx = tid; idx < 10368; idx += 256) {
      int ci = idx / 324, r = idx % 324, yy = r / 18, xc = r % 18;
      int yg = yy - 1, xg = xc - 1;
      float v = 0.f;
      if ((unsigned)yg < 16u && (unsigned)xg < 16u)
        v = p1[((b * 64 + h * 32 + ci) * 16 + yg) * 16 + xg];
      in_s[idx] = v;
    }
    __syncthreads();
    for (int ci = 0; ci < 32; ++ci) {
#pragma unroll
      for (int kk = 0; kk < 9; ++kk) {
        int ky = kk / 3, kx = kk % 3;
        float in = in_s[ci * 324 + (y + ky) * 18 + (xx + kx)];
        const float4* wp = (const float4*)(w2t + ((kk * 64 + h * 32 + ci) * 128 + cog * 16));
        float4 a0 = wp[0], a1 = wp[1], a2 = wp[2], a3 = wp[3];  // uniform -> s_load
        acc[0]  = fmaf(in, a0.x, acc[0]);  acc[1]  = fmaf(in, a0.y, acc[1]);
        acc[2]  = fmaf(in, a0.z, acc[2]);  acc[3]  = fmaf(in, a0.w, acc[3]);
        acc[4]  = fmaf(in, a1.x, acc[4]);  acc[5]  = fmaf(in, a1.y, acc[5]);
        acc[6]  = fmaf(in, a1.z, acc[6]);  acc[7]  = fmaf(in, a1.w, acc[7]);
        acc[8]  = fmaf(in, a2.x, acc[8]);  acc[9]  = fmaf(in, a2.y, acc[9]);
        acc[10] = fmaf(in, a2.z, acc[10]); acc[11] = fmaf(in, a2.w, acc[11]);
        acc[12] = fmaf(in, a3.x, acc[12]); acc[13] = fmaf(in, a3.y, acc[13]);
        acc[14] = fmaf(in, a3.z, acc[14]); acc[15] = fmaf(in, a3.w, acc[15]);
      }
    }
  }
  __syncthreads();
#pragma unroll
  for (int c = 0; c < 16; ++c) {
    int co = cog * 16 + c;
    float v = fmaxf(fmaf(acc[c], wsc[WS_BN + 128 + co], wsc[WS_BN + 256 + co]), 0.f);
    pb[c * 256 + y * 16 + xx] = v;
  }
  __syncthreads();
  if (tid < 64) {
    int py = tid >> 3, px = tid & 7;
#pragma unroll
    for (int c = 0; c < 16; ++c) {
      const float* q = &pb[c * 256 + (2 * py) * 16 + 2 * px];
      float m = fmaxf(fmaxf(q[0], q[1]), fmaxf(q[16], q[17]));
      int co = cog * 16 + c;
      int fi = b * 8192 + co * 64 + py * 8 + px;
      p2f[fi] = m;
      out[32 + fi] = m;
    }
  }
}

// ---------------- k3b: fmax over f ----------------
__global__ __launch_bounds__(256) void k3b_fmax(const float* __restrict__ p2f,
                                                float* __restrict__ ws)
{
  int idx = blockIdx.x * 256 + threadIdx.x;   // 65536 float4s exactly
  float4 v = *(const float4*)(p2f + idx * 4);
  float m = fmaxf(fmaxf(v.x, v.y), fmaxf(v.z, v.w));
#pragma unroll
  for (int off = 32; off > 0; off >>= 1) m = fmaxf(m, __shfl_xor(m, off));
  if ((threadIdx.x & 63) == 0) atomicMax((int*)(ws + WS_FMAX), __float_as_int(m));
}

// ---------------- k3c: quantize f -> u8 ----------------
__global__ __launch_bounds__(256) void k3c_quant(const float* __restrict__ p2f,
                                                 const float* __restrict__ wsc,
                                                 unsigned* __restrict__ fq)
{
  int wid = blockIdx.x * 256 + threadIdx.x;   // 65536 words exactly
  float kq = 255.0f / wsc[WS_FMAX];
  float4 v = *(const float4*)(p2f + wid * 4);
  unsigned q0 = (unsigned)fmaf(v.x, kq, 0.5f);
  unsigned q1 = (unsigned)fmaf(v.y, kq, 0.5f);
  unsigned q2 = (unsigned)fmaf(v.z, kq, 0.5f);
  unsigned q3 = (unsigned)fmaf(v.w, kq, 0.5f);
  fq[wid] = q0 | (q1 << 8) | (q2 << 16) | (q3 << 24);
}

// ---------------- k4: L1-kNN via v_sad_u8 ----------------
// grid = (157 n-tiles of 128, 8 d-splits of 1024). 4 waves; wave w owns dims
// [s*1024+w*256, +256) in chunks of 32. Per-wave LDS: f [32 rows][32B] u8 (1KB),
// n [128 rows][48B stride] u8 (6KB). Thread tile 8b x 8n, 2 sad-words per step.
// NOTE: no min-occupancy bound — live state is ~112 VGPR (acc 64 + fv/nv 32 +
// staging). Round-7's (256,4) capped VGPRs at 64 -> ~850 MB scratch-spill
// traffic per launch (WRITE_SIZE evidence). Default 256-VGPR budget -> no spill.
__global__ __launch_bounds__(256) void k4_knn(
    const float* __restrict__ nbr, const unsigned* __restrict__ fq,
    const float* __restrict__ wsc, float* __restrict__ l1p)
{
  __shared__ __align__(16) char smem[28672];
  const int tid = threadIdx.x;
  const int w = tid >> 6, lane = tid & 63;
  const int b_thr = lane >> 4;    // 0..3
  const int n_thr = lane & 15;    // 0..15
  const int n0 = blockIdx.x * 128;
  const int s = blockIdx.y;
  const int dbase = s * 1024 + w * 256;
  char* ft = smem + w * 7168;
  char* nt = ft + 1024;
  const float kq = 255.0f / wsc[WS_FMAX];

  unsigned acc[8][8];
#pragma unroll
  for (int i = 0; i < 8; ++i)
#pragma unroll
    for (int j = 0; j < 8; ++j) acc[i][j] = 0u;

#pragma unroll 1
  for (int ch = 0; ch < 8; ++ch) {
    const int dc = dbase + ch * 32;
    __syncthreads();
    // stage f tile: 32 rows x 8 words (already u8)
#pragma unroll
    for (int t = 0; t < 4; ++t) {
      int uu = t * 64 + lane;
      int row = uu >> 3, wd = uu & 7;
      unsigned v = fq[row * 2048 + (dc >> 2) + wd];
      *(unsigned*)(ft + row * 32 + wd * 4) = v;
    }
    // stage n tile: 128 rows x 32 dims fp32 -> u8 quantize+pack
#pragma unroll
    for (int t = 0; t < 16; ++t) {
      int uu = t * 64 + lane;
      int row = uu >> 3, g = uu & 7;
      int nn = n0 + row; if (nn > 19999) nn = 19999;
      float4 v = *(const float4*)(nbr + (size_t)nn * 8192 + dc + g * 4);
      unsigned q0 = (unsigned)fmaf(v.x, kq, 0.5f);
      unsigned q1 = (unsigned)fmaf(v.y, kq, 0.5f);
      unsigned q2 = (unsigned)fmaf(v.z, kq, 0.5f);
      unsigned q3 = (unsigned)fmaf(v.w, kq, 0.5f);
      *(unsigned*)(nt + row * 48 + g * 4) = q0 | (q1 << 8) | (q2 << 16) | (q3 << 24);
    }
    __syncthreads();
#pragma unroll
    for (int h = 0; h < 4; ++h) {      // 8 dims (2 sad-words) per h
      uint2 fv[8], nv[8];
#pragma unroll
      for (int i = 0; i < 8; ++i)
        fv[i] = *(const uint2*)(ft + (b_thr + 4 * i) * 32 + h * 8);
#pragma unroll
      for (int j = 0; j < 8; ++j)
        nv[j] = *(const uint2*)(nt + (n_thr + 16 * j) * 48 + h * 8);
#pragma unroll
      for (int i = 0; i < 8; ++i)
#pragma unroll
        for (int j = 0; j < 8; ++j)
          acc[i][j] = sad4(fv[i].y, nv[j].y, sad4(fv[i].x, nv[j].x, acc[i][j]));
    }
  }

  // cross-wave reduce, 4 quarters of 8 b-rows (16 KB overlay)
  unsigned* red = (unsigned*)smem;
  __syncthreads();
#pragma unroll 1
  for (int qt = 0; qt < 4; ++qt) {
#pragma unroll
    for (int ii = 0; ii < 2; ++ii) {
      int i = qt * 2 + ii;
      int brow8 = ii * 4 + b_thr;
#pragma unroll
      for (int j = 0; j < 8; ++j)
        red[(brow8 * 128 + n_thr + 16 * j) * 4 + w] = acc[i][j];
    }
    __syncthreads();
#pragma unroll
    for (int k = 0; k < 4; ++k) {
      int e = k * 256 + tid;
      uint4 v = *(const uint4*)(red + e * 4);
      int brow = qt * 8 + (e >> 7), n = e & 127;
      l1p[(s * 32 + brow) * 20096 + n0 + n] = (float)(v.x + v.y + v.z + v.w);
    }
    __syncthreads();
  }
}

// ---------------- k5: reduce splits, exp-weight, mask, accumulate nr/dr ----------------
__global__ __launch_bounds__(256) void k5_red(
    const float* __restrict__ l1p, const int* __restrict__ labels,
    const float* __restrict__ wsc, float* __restrict__ nrdr)
{
  int b = blockIdx.y;
  int n = blockIdx.x * 256 + (int)threadIdx.x;
  int pred = ((const int*)(wsc + WS_PRED))[0];
  float c = wsc[WS_FMAX] * (-1.0f / (255.0f * 1000.0f));
  float wgt = 0.f, mk = 0.f;
  if (n < 20000) {
    float L1 = 0.f;
#pragma unroll
    for (int s2 = 0; s2 < 8; ++s2) L1 += l1p[(s2 * 32 + b) * 20096 + n];
    wgt = __expf(L1 * c);
    if (labels[n] == pred) mk = wgt;
  }
#pragma unroll
  for (int off = 32; off > 0; off >>= 1) {
    wgt += __shfl_xor(wgt, off);
    mk  += __shfl_xor(mk, off);
  }
  if ((threadIdx.x & 63) == 0) {
    atomicAdd(&nrdr[b], mk);
    atomicAdd(&nrdr[32 + b], wgt);
  }
}

// ---------------- k6: final ratio ----------------
__global__ void k6_out(const float* __restrict__ nrdr, float* __restrict__ out)
{
  int t = threadIdx.x;
  if (t < 32) out[t] = nrdr[t] / nrdr[32 + t];
}

extern "C" void kernel_launch(void* const* d_in, const int* in_sizes, int n_in,
                              void* d_out, int out_size, void* d_ws, size_t ws_size,
                              hipStream_t stream)
{
  (void)in_sizes; (void)n_in; (void)out_size; (void)ws_size;
  const float* x    = (const float*)d_in[0];
  const float* w1   = (const float*)d_in[1];
  const float* c1b  = (const float*)d_in[2];
  const float* g1   = (const float*)d_in[3];
  const float* be1  = (const float*)d_in[4];
  const float* m1   = (const float*)d_in[5];
  const float* v1   = (const float*)d_in[6];
  const float* w2   = (const float*)d_in[7];
  const float* c2b  = (const float*)d_in[8];
  const float* g2   = (const float*)d_in[9];
  const float* be2  = (const float*)d_in[10];
  const float* m2   = (const float*)d_in[11];
  const float* v2   = (const float*)d_in[12];
  const float* nbrf = (const float*)d_in[13];
  const int* labels = (const int*)d_in[14];
  float* ws = (float*)d_ws;
  float* out = (float*)d_out;

  k0a_init<<<1, 256, 0, stream>>>(c1b, g1, be1, m1, v1, c2b, g2, be2, m2, v2, ws);
  k0b_hist<<<20, 256, 0, stream>>>(labels, ws);
  k0c_mode<<<1, 64, 0, stream>>>(ws);
  k1_w2t<<<288, 256, 0, stream>>>(w2, ws + WS_W2T);
  k2_conv1<<<512, 256, 0, stream>>>(x, w1, ws, ws + WS_P1);
  k3_conv2<<<256, 256, 0, stream>>>(ws + WS_P1, ws + WS_W2T, ws, ws + WS_P2F, out);
  k3b_fmax<<<256, 256, 0, stream>>>(ws + WS_P2F, ws);
  k3c_quant<<<256, 256, 0, stream>>>(ws + WS_P2F, ws, (unsigned*)(ws + WS_FQ));
  k4_knn<<<dim3(157, 8), 256, 0, stream>>>(nbrf, (const unsigned*)(ws + WS_FQ), ws, ws + WS_L1P);
  k5_red<<<dim3(79, 32), 256, 0, stream>>>(ws + WS_L1P, labels, ws, ws + WS_NR);
  k6_out<<<1, 64, 0, stream>>>(ws + WS_NR, out);
}

// Round 9
// 419.325 us; speedup vs baseline: 1.6498x; 1.1657x over previous
//
#include <hip/hip_runtime.h>
#include <stdint.h>

// ---- workspace layout (float offsets) ----
#define WS_FQ    0u          // f quantized u8 [32][8192] = 65536 floats (as u32 words)
#define WS_BN    65536u      // A1[64] B1[64] A2[128] B2[128]
#define WS_NR    65920u      // nr[32] dr[32]
#define WS_CNT   65985u      // int[10]
#define WS_FMAX  65995u      // float (atomicMax as int)
#define WS_X     66048u      // overlay region:
#define WS_P1    WS_X                  // conv: [32][64][16][16] = 524288
#define WS_W2T   (WS_X + 524288u)      // conv: [9][64][128]     = 73728
#define WS_P2F   (WS_X + 598016u)      // conv: [32][8192] f32   = 262144
#define WS_L1P   WS_X                  // knn:  [8][32][20096]   = 5144576

__device__ __forceinline__ unsigned sad4(unsigned a, unsigned b, unsigned c) {
#if __has_builtin(__builtin_amdgcn_sad_u8)
  return __builtin_amdgcn_sad_u8(a, b, c);
#else
  unsigned d;
  asm("v_sad_u8 %0, %1, %2, %3" : "=v"(d) : "v"(a), "v"(b), "v"(c));
  return d;
#endif
}

// ---------------- k0a: init + BN fold ----------------
__global__ __launch_bounds__(256) void k0a_init(
    const float* __restrict__ c1b, const float* __restrict__ g1,
    const float* __restrict__ be1, const float* __restrict__ m1,
    const float* __restrict__ v1,
    const float* __restrict__ c2b, const float* __restrict__ g2,
    const float* __restrict__ be2, const float* __restrict__ m2,
    const float* __restrict__ v2,
    float* __restrict__ ws)
{
  int tid = threadIdx.x;
  if (tid < 64) ws[WS_NR + tid] = 0.f;
  if (tid >= 192 && tid < 202) ((int*)(ws + WS_CNT))[tid - 192] = 0;
  if (tid == 202) ws[WS_FMAX] = 2.0f;
  if (tid < 64) {
    float A = g1[tid] * __frsqrt_rn(v1[tid] + 1e-5f);
    ws[WS_BN + tid] = A;
    ws[WS_BN + 64 + tid] = (c1b[tid] - m1[tid]) * A + be1[tid];
  } else if (tid < 192) {
    int c = tid - 64;
    float A = g2[c] * __frsqrt_rn(v2[c] + 1e-5f);
    ws[WS_BN + 128 + c] = A;
    ws[WS_BN + 256 + c] = (c2b[c] - m2[c]) * A + be2[c];
  }
}

// ---------------- k0b: label histogram (20 blocks, global atomics) ----------------
__global__ __launch_bounds__(256) void k0b_hist(const int* __restrict__ labels,
                                                float* __restrict__ ws)
{
  __shared__ int cnt[10];
  int tid = threadIdx.x;
  if (tid < 10) cnt[tid] = 0;
  __syncthreads();
  int i0 = (blockIdx.x * 256 + tid) * 4;
  if (i0 + 3 < 20000) {
    int4 v = *(const int4*)(labels + i0);
    atomicAdd(&cnt[v.x], 1);
    atomicAdd(&cnt[v.y], 1);
    atomicAdd(&cnt[v.z], 1);
    atomicAdd(&cnt[v.w], 1);
  }
  __syncthreads();
  if (tid < 10) atomicAdd((int*)(ws + WS_CNT) + tid, cnt[tid]);
}

// ---------------- k1: transpose conv2 weights -> [kk][ci][co] ----------------
__global__ __launch_bounds__(256) void k1_w2t(const float* __restrict__ w2,
                                              float* __restrict__ w2t)
{
  int idx = blockIdx.x * 256 + threadIdx.x;
  if (idx >= 73728) return;
  int co = idx / 576, r = idx % 576, ci = r / 9, kk = r % 9;
  w2t[(kk * 64 + ci) * 128 + co] = w2[idx];
}

// ---------------- k2: conv1 + BN + ReLU + 2x2 maxpool ----------------
__global__ __launch_bounds__(256) void k2_conv1(
    const float* __restrict__ x, const float* __restrict__ w1,
    const float* __restrict__ wsc, float* __restrict__ p1)
{
  __shared__ float xs[3 * 34 * 34];
  int tid = threadIdx.x;
  int b = blockIdx.x >> 4, cog = blockIdx.x & 15;

  for (int idx = tid; idx < 3 * 34 * 34; idx += 256) {
    int ci = idx / 1156, r = idx % 1156, yy = r / 34, xc = r % 34;
    int yg = yy - 1, xg = xc - 1;
    float v = 0.f;
    if ((unsigned)yg < 32u && (unsigned)xg < 32u)
      v = x[((b * 3 + ci) * 32 + yg) * 32 + xg];
    xs[idx] = v;
  }
  __syncthreads();

  int py = tid >> 4, px = tid & 15;
  float acc[4][4] = {};
#pragma unroll
  for (int ci = 0; ci < 3; ++ci)
#pragma unroll
    for (int ky = 0; ky < 3; ++ky)
#pragma unroll
      for (int kx = 0; kx < 3; ++kx) {
        const float* xp = &xs[ci * 1156 + (2 * py + ky) * 34 + (2 * px + kx)];
        float i00 = xp[0], i01 = xp[1], i10 = xp[34], i11 = xp[35];
#pragma unroll
        for (int c = 0; c < 4; ++c) {
          float wv = w1[cog * 108 + c * 27 + ci * 9 + ky * 3 + kx];  // uniform -> s_load
          acc[c][0] = fmaf(i00, wv, acc[c][0]);
          acc[c][1] = fmaf(i01, wv, acc[c][1]);
          acc[c][2] = fmaf(i10, wv, acc[c][2]);
          acc[c][3] = fmaf(i11, wv, acc[c][3]);
        }
      }
#pragma unroll
  for (int c = 0; c < 4; ++c) {
    int co = cog * 4 + c;
    float A = wsc[WS_BN + co], B = wsc[WS_BN + 64 + co];
    float v0 = fmaxf(fmaf(acc[c][0], A, B), 0.f);
    float v1 = fmaxf(fmaf(acc[c][1], A, B), 0.f);
    float v2 = fmaxf(fmaf(acc[c][2], A, B), 0.f);
    float v3 = fmaxf(fmaf(acc[c][3], A, B), 0.f);
    float m = fmaxf(fmaxf(v0, v1), fmaxf(v2, v3));
    p1[((b * 64 + co) * 16 + py) * 16 + px] = m;
  }
}

// ---------------- k3: conv2 + BN + ReLU + pool + fused block fmax ----------------
__global__ __launch_bounds__(256) void k3_conv2(
    const float* __restrict__ p1, const float* __restrict__ w2t,
    const float* __restrict__ wsc, float* __restrict__ p2f,
    float* __restrict__ out, float* __restrict__ ws)
{
  __shared__ float in_s[32 * 324];  // 40.5 KB
  __shared__ float pb[4096];        // 16 KB pool buffer
  int tid = threadIdx.x;
  int b = blockIdx.x >> 3, cog = blockIdx.x & 7;
  int y = tid >> 4, xx = tid & 15;

  float acc[16];
#pragma unroll
  for (int c = 0; c < 16; ++c) acc[c] = 0.f;

  for (int h = 0; h < 2; ++h) {
    __syncthreads();
    for (int idx = tid; idx < 10368; idx += 256) {
      int ci = idx / 324, r = idx % 324, yy = r / 18, xc = r % 18;
      int yg = yy - 1, xg = xc - 1;
      float v = 0.f;
      if ((unsigned)yg < 16u && (unsigned)xg < 16u)
        v = p1[((b * 64 + h * 32 + ci) * 16 + yg) * 16 + xg];
      in_s[idx] = v;
    }
    __syncthreads();
    for (int ci = 0; ci < 32; ++ci) {
#pragma unroll
      for (int kk = 0; kk < 9; ++kk) {
        int ky = kk / 3, kx = kk % 3;
        float in = in_s[ci * 324 + (y + ky) * 18 + (xx + kx)];
        const float4* wp = (const float4*)(w2t + ((kk * 64 + h * 32 + ci) * 128 + cog * 16));
        float4 a0 = wp[0], a1 = wp[1], a2 = wp[2], a3 = wp[3];  // uniform -> s_load
        acc[0]  = fmaf(in, a0.x, acc[0]);  acc[1]  = fmaf(in, a0.y, acc[1]);
        acc[2]  = fmaf(in, a0.z, acc[2]);  acc[3]  = fmaf(in, a0.w, acc[3]);
        acc[4]  = fmaf(in, a1.x, acc[4]);  acc[5]  = fmaf(in, a1.y, acc[5]);
        acc[6]  = fmaf(in, a1.z, acc[6]);  acc[7]  = fmaf(in, a1.w, acc[7]);
        acc[8]  = fmaf(in, a2.x, acc[8]);  acc[9]  = fmaf(in, a2.y, acc[9]);
        acc[10] = fmaf(in, a2.z, acc[10]); acc[11] = fmaf(in, a2.w, acc[11]);
        acc[12] = fmaf(in, a3.x, acc[12]); acc[13] = fmaf(in, a3.y, acc[13]);
        acc[14] = fmaf(in, a3.z, acc[14]); acc[15] = fmaf(in, a3.w, acc[15]);
      }
    }
  }
  __syncthreads();
#pragma unroll
  for (int c = 0; c < 16; ++c) {
    int co = cog * 16 + c;
    float v = fmaxf(fmaf(acc[c], wsc[WS_BN + 128 + co], wsc[WS_BN + 256 + co]), 0.f);
    pb[c * 256 + y * 16 + xx] = v;
  }
  __syncthreads();
  if (tid < 64) {
    int py = tid >> 3, px = tid & 7;
    float lmax = 0.f;   // post-ReLU values are >= 0
#pragma unroll
    for (int c = 0; c < 16; ++c) {
      const float* q = &pb[c * 256 + (2 * py) * 16 + 2 * px];
      float m = fmaxf(fmaxf(q[0], q[1]), fmaxf(q[16], q[17]));
      int co = cog * 16 + c;
      int fi = b * 8192 + co * 64 + py * 8 + px;
      p2f[fi] = m;
      out[32 + fi] = m;
      lmax = fmaxf(lmax, m);
    }
    // fused global-max (replaces k3b): single-wave reduce + one atomic
#pragma unroll
    for (int off = 32; off > 0; off >>= 1) lmax = fmaxf(lmax, __shfl_xor(lmax, off));
    if (tid == 0) atomicMax((int*)(ws + WS_FMAX), __float_as_int(lmax));
  }
}

// ---------------- k3c: quantize f -> u8 ----------------
__global__ __launch_bounds__(256) void k3c_quant(const float* __restrict__ p2f,
                                                 const float* __restrict__ wsc,
                                                 unsigned* __restrict__ fq)
{
  int wid = blockIdx.x * 256 + threadIdx.x;   // 65536 words exactly
  float kq = 255.0f / wsc[WS_FMAX];
  float4 v = *(const float4*)(p2f + wid * 4);
  unsigned q0 = (unsigned)fmaf(v.x, kq, 0.5f);
  unsigned q1 = (unsigned)fmaf(v.y, kq, 0.5f);
  unsigned q2 = (unsigned)fmaf(v.z, kq, 0.5f);
  unsigned q3 = (unsigned)fmaf(v.w, kq, 0.5f);
  fq[wid] = q0 | (q1 << 8) | (q2 << 16) | (q3 << 24);
}

// ---------------- k4: L1-kNN via v_sad_u8, wave-private no-barrier pipeline ----
// grid = (157 n-tiles of 128, 8 d-splits of 1024). 4 waves/block; wave w owns
// dims [s*1024 + w*256, +256) as 4 chunks of 64. LDS per wave (PRIVATE — no
// __syncthreads in main loop; in-wave LDS ordering suffices):
//   n tile [128 rows][64 B u8] = 8 KB, slot-XOR swizzled (2-way max = free)
//   f tile [ 32 rows][64 B u8] = 2 KB, unswizzled (2-way max)
// Thread tile: B_rep 8 (all 32 b: b_lane 0..3 x 4i) x N_rep 8 (n_lane 0..15 x 16j).
// All ds_read addresses affine -> base + imm offset, zero per-read VALU.
__global__ __launch_bounds__(256) void k4_knn(
    const float* __restrict__ nbr, const unsigned* __restrict__ fq,
    const float* __restrict__ wsc, float* __restrict__ l1p)
{
  __shared__ __align__(16) char smem[40960];  // 4 x (8KB n + 2KB f)
  const int tid = threadIdx.x;
  const int w = tid >> 6, lane = tid & 63;
  const int b_lane = lane & 3;    // 0..3
  const int n_lane = lane >> 2;   // 0..15
  const int n0 = blockIdx.x * 128;
  const int s = blockIdx.y;
  const int dbase = s * 1024 + w * 256;
  char* nt = smem + w * 10240;
  char* ft = nt + 8192;
  const float kq = 255.0f / wsc[WS_FMAX];
  const int chi = (n_lane >> 1) & 3;   // read-side swizzle xor (j-invariant)

  unsigned acc[8][8];
#pragma unroll
  for (int i = 0; i < 8; ++i)
#pragma unroll
    for (int j = 0; j < 8; ++j) acc[i][j] = 0u;

#pragma unroll 1
  for (int ch = 0; ch < 4; ++ch) {
    const int dc = dbase + ch * 64;
    // ---- stage n: 128 rows x 64 dims fp32 -> u8. id = k*64+lane: 1KB-coalesced
    // per inst. write addr = row*64 + ((f4>>2)^((row>>1)&3))*16 + (f4&3)*4.
#pragma unroll 8
    for (int k = 0; k < 32; ++k) {
      int id = k * 64 + lane;
      int row = id >> 4, f4 = id & 15;
      int nn = n0 + row; if (nn > 19999) nn = 19999;
      float4 v = *(const float4*)(nbr + (size_t)nn * 8192 + dc + f4 * 4);
      unsigned q0 = (unsigned)fmaf(v.x, kq, 0.5f);
      unsigned q1 = (unsigned)fmaf(v.y, kq, 0.5f);
      unsigned q2 = (unsigned)fmaf(v.z, kq, 0.5f);
      unsigned q3 = (unsigned)fmaf(v.w, kq, 0.5f);
      int slot = (f4 >> 2) ^ ((row >> 1) & 3);
      *(unsigned*)(nt + row * 64 + (slot << 4) + (f4 & 3) * 4) =
          q0 | (q1 << 8) | (q2 << 16) | (q3 << 24);
    }
    // ---- stage f: 32 rows x 16 words (already u8 in fq), unswizzled ----
#pragma unroll
    for (int k = 0; k < 8; ++k) {
      int id = k * 64 + lane;
      int row = id >> 4, wd = id & 15;
      unsigned v = fq[row * 2048 + (dc >> 2) + wd];
      *(unsigned*)(ft + row * 64 + wd * 4) = v;
    }
    // ---- compute: 4 g-groups of 16 B; 8x8 pairs x uint4 sads ----
#pragma unroll
    for (int g = 0; g < 4; ++g) {
      const char* fb = ft + b_lane * 64 + g * 16;
      const char* nb = nt + n_lane * 64 + ((g ^ chi) << 4);
      uint4 fv[8], nv[8];
#pragma unroll
      for (int i = 0; i < 8; ++i) fv[i] = *(const uint4*)(fb + i * 256);
#pragma unroll
      for (int j = 0; j < 8; ++j) nv[j] = *(const uint4*)(nb + j * 1024);
#pragma unroll
      for (int i = 0; i < 8; ++i)
#pragma unroll
        for (int j = 0; j < 8; ++j) {
          unsigned t0 = sad4(fv[i].x, nv[j].x, acc[i][j]);
          t0 = sad4(fv[i].y, nv[j].y, t0);
          t0 = sad4(fv[i].z, nv[j].z, t0);
          acc[i][j] = sad4(fv[i].w, nv[j].w, t0);
        }
    }
  }

  // cross-wave reduce, 2 halves of 16 b-rows (32 KB overlay aliases tiles)
  unsigned* red = (unsigned*)smem;
#pragma unroll
  for (int r = 0; r < 2; ++r) {
    __syncthreads();
#pragma unroll
    for (int ii = 0; ii < 4; ++ii) {
#pragma unroll
      for (int j = 0; j < 8; ++j) {
        int b16 = b_lane + 4 * ii;            // 0..15 within this half
        int n = n_lane + 16 * j;
        red[(b16 * 128 + n) * 4 + w] = acc[r * 4 + ii][j];
      }
    }
    __syncthreads();
#pragma unroll
    for (int k = 0; k < 8; ++k) {
      int e = k * 256 + tid;                  // 0..2047
      uint4 v = *(const uint4*)(red + e * 4);
      int b = 16 * r + (e >> 7), n = e & 127; // b = b_lane + 4i + 16r mapping
      l1p[(s * 32 + b) * 20096 + n0 + n] = (float)(v.x + v.y + v.z + v.w);
    }
  }
}

// ---------------- k5: reduce splits, exp-weight, mask (mode inlined) ----------------
__global__ __launch_bounds__(256) void k5_red(
    const float* __restrict__ l1p, const int* __restrict__ labels,
    const float* __restrict__ wsc, float* __restrict__ nrdr)
{
  int b = blockIdx.y;
  int n = blockIdx.x * 256 + (int)threadIdx.x;
  // mode(labels) from the global histogram (k0b); ties -> smallest index
  const int* cnt = (const int*)(wsc + WS_CNT);
  int best = 0;
#pragma unroll
  for (int c = 1; c < 10; ++c) best = (cnt[c] > cnt[best]) ? c : best;
  float kc = wsc[WS_FMAX] * (-1.0f / (255.0f * 1000.0f));
  float wgt = 0.f, mk = 0.f;
  if (n < 20000) {
    float L1 = 0.f;
#pragma unroll
    for (int s2 = 0; s2 < 8; ++s2) L1 += l1p[(s2 * 32 + b) * 20096 + n];
    wgt = __expf(L1 * kc);
    if (labels[n] == best) mk = wgt;
  }
#pragma unroll
  for (int off = 32; off > 0; off >>= 1) {
    wgt += __shfl_xor(wgt, off);
    mk  += __shfl_xor(mk, off);
  }
  if ((threadIdx.x & 63) == 0) {
    atomicAdd(&nrdr[b], mk);
    atomicAdd(&nrdr[32 + b], wgt);
  }
}

// ---------------- k6: final ratio ----------------
__global__ void k6_out(const float* __restrict__ nrdr, float* __restrict__ out)
{
  int t = threadIdx.x;
  if (t < 32) out[t] = nrdr[t] / nrdr[32 + t];
}

extern "C" void kernel_launch(void* const* d_in, const int* in_sizes, int n_in,
                              void* d_out, int out_size, void* d_ws, size_t ws_size,
                              hipStream_t stream)
{
  (void)in_sizes; (void)n_in; (void)out_size; (void)ws_size;
  const float* x    = (const float*)d_in[0];
  const float* w1   = (const float*)d_in[1];
  const float* c1b  = (const float*)d_in[2];
  const float* g1   = (const float*)d_in[3];
  const float* be1  = (const float*)d_in[4];
  const float* m1   = (const float*)d_in[5];
  const float* v1   = (const float*)d_in[6];
  const float* w2   = (const float*)d_in[7];
  const float* c2b  = (const float*)d_in[8];
  const float* g2   = (const float*)d_in[9];
  const float* be2  = (const float*)d_in[10];
  const float* m2   = (const float*)d_in[11];
  const float* v2   = (const float*)d_in[12];
  const float* nbrf = (const float*)d_in[13];
  const int* labels = (const int*)d_in[14];
  float* ws = (float*)d_ws;
  float* out = (float*)d_out;

  k0a_init<<<1, 256, 0, stream>>>(c1b, g1, be1, m1, v1, c2b, g2, be2, m2, v2, ws);
  k0b_hist<<<20, 256, 0, stream>>>(labels, ws);
  k1_w2t<<<288, 256, 0, stream>>>(w2, ws + WS_W2T);
  k2_conv1<<<512, 256, 0, stream>>>(x, w1, ws, ws + WS_P1);
  k3_conv2<<<256, 256, 0, stream>>>(ws + WS_P1, ws + WS_W2T, ws, ws + WS_P2F, out, ws);
  k3c_quant<<<256, 256, 0, stream>>>(ws + WS_P2F, ws, (unsigned*)(ws + WS_FQ));
  k4_knn<<<dim3(157, 8), 256, 0, stream>>>(nbrf, (const unsigned*)(ws + WS_FQ), ws, ws + WS_L1P);
  k5_red<<<dim3(79, 32), 256, 0, stream>>>(ws + WS_L1P, labels, ws, ws + WS_NR);
  k6_out<<<1, 64, 0, stream>>>(ws + WS_NR, out);
}

// Round 10
// 382.160 us; speedup vs baseline: 1.8103x; 1.0972x over previous
//
#include <hip/hip_runtime.h>
#include <stdint.h>

// ---- workspace layout (float offsets) ----
#define WS_BN    0u        // A1[64] B1[64] A2[128] B2[128] = 384
#define WS_NR    384u      // nr[32] dr[32]
#define WS_FMAX  448u      // float (atomicMax as int)
#define WS_CTR   449u      // int ticket counter for k5 last-block
#define WS_CNTP  450u      // int[20][10] histogram partials (slot-written, no zero needed)
#define WS_P2F   768u      // [32][8192] f fp32 = 262144 (persistent through k4)
#define WS_X     262912u   // overlay:
#define WS_P1    WS_X                 // conv: [32][64][16][16] = 524288
#define WS_W2T   (WS_X + 524288u)     // conv: [9][64][128]     = 73728
#define WS_L1P   WS_X                 // knn:  [8][32][20096]   = 5144576

typedef float f4v __attribute__((ext_vector_type(4)));

__device__ __forceinline__ unsigned sad4(unsigned a, unsigned b, unsigned c) {
#if __has_builtin(__builtin_amdgcn_sad_u8)
  return __builtin_amdgcn_sad_u8(a, b, c);
#else
  unsigned d;
  asm("v_sad_u8 %0, %1, %2, %3" : "=v"(d) : "v"(a), "v"(b), "v"(c));
  return d;
#endif
}

// ---------------- prep: BN fold + zeros | label histogram partials | w2t ----
// block 0: BN fold, zero nr/dr, fmax=2, ctr=0
// blocks 1..20: histogram of labels[(blk-1)*1000 .. +1000) -> cntp[blk-1][10] (overwrite)
// blocks 21..308: w2t transpose
__global__ __launch_bounds__(256) void prep(
    const int* __restrict__ labels, const float* __restrict__ w2,
    const float* __restrict__ c1b, const float* __restrict__ g1,
    const float* __restrict__ be1, const float* __restrict__ m1,
    const float* __restrict__ v1,
    const float* __restrict__ c2b, const float* __restrict__ g2,
    const float* __restrict__ be2, const float* __restrict__ m2,
    const float* __restrict__ v2,
    float* __restrict__ ws)
{
  int blk = blockIdx.x, tid = threadIdx.x;
  if (blk == 0) {
    if (tid < 64) {
      ws[WS_NR + tid] = 0.f;
      float A = g1[tid] * __frsqrt_rn(v1[tid] + 1e-5f);
      ws[WS_BN + tid] = A;
      ws[WS_BN + 64 + tid] = (c1b[tid] - m1[tid]) * A + be1[tid];
    } else if (tid < 192) {
      int c = tid - 64;
      float A = g2[c] * __frsqrt_rn(v2[c] + 1e-5f);
      ws[WS_BN + 128 + c] = A;
      ws[WS_BN + 256 + c] = (c2b[c] - m2[c]) * A + be2[c];
    } else if (tid == 192) {
      ws[WS_FMAX] = 2.0f;
    } else if (tid == 193) {
      ((int*)ws)[WS_CTR] = 0;
    }
  } else if (blk <= 20) {
    __shared__ int cnt[10];
    if (tid < 10) cnt[tid] = 0;
    __syncthreads();
    int base = (blk - 1) * 1000;
    for (int i = base + tid; i < base + 1000; i += 256)
      atomicAdd(&cnt[labels[i]], 1);
    __syncthreads();
    if (tid < 10) ((int*)(ws + WS_CNTP))[(blk - 1) * 10 + tid] = cnt[tid];
  } else {
    int idx = (blk - 21) * 256 + tid;
    if (idx < 73728) {
      int co = idx / 576, r = idx % 576, ci = r / 9, kk = r % 9;
      ws[WS_W2T + (kk * 64 + ci) * 128 + co] = w2[idx];
    }
  }
}

// ---------------- k2: conv1 + BN + ReLU + 2x2 maxpool ----------------
__global__ __launch_bounds__(256) void k2_conv1(
    const float* __restrict__ x, const float* __restrict__ w1,
    const float* __restrict__ wsc, float* __restrict__ p1)
{
  __shared__ float xs[3 * 34 * 34];
  int tid = threadIdx.x;
  int b = blockIdx.x >> 4, cog = blockIdx.x & 15;

  for (int idx = tid; idx < 3 * 34 * 34; idx += 256) {
    int ci = idx / 1156, r = idx % 1156, yy = r / 34, xc = r % 34;
    int yg = yy - 1, xg = xc - 1;
    float v = 0.f;
    if ((unsigned)yg < 32u && (unsigned)xg < 32u)
      v = x[((b * 3 + ci) * 32 + yg) * 32 + xg];
    xs[idx] = v;
  }
  __syncthreads();

  int py = tid >> 4, px = tid & 15;
  float acc[4][4] = {};
#pragma unroll
  for (int ci = 0; ci < 3; ++ci)
#pragma unroll
    for (int ky = 0; ky < 3; ++ky)
#pragma unroll
      for (int kx = 0; kx < 3; ++kx) {
        const float* xp = &xs[ci * 1156 + (2 * py + ky) * 34 + (2 * px + kx)];
        float i00 = xp[0], i01 = xp[1], i10 = xp[34], i11 = xp[35];
#pragma unroll
        for (int c = 0; c < 4; ++c) {
          float wv = w1[cog * 108 + c * 27 + ci * 9 + ky * 3 + kx];  // uniform -> s_load
          acc[c][0] = fmaf(i00, wv, acc[c][0]);
          acc[c][1] = fmaf(i01, wv, acc[c][1]);
          acc[c][2] = fmaf(i10, wv, acc[c][2]);
          acc[c][3] = fmaf(i11, wv, acc[c][3]);
        }
      }
#pragma unroll
  for (int c = 0; c < 4; ++c) {
    int co = cog * 4 + c;
    float A = wsc[WS_BN + co], B = wsc[WS_BN + 64 + co];
    float v0 = fmaxf(fmaf(acc[c][0], A, B), 0.f);
    float v1 = fmaxf(fmaf(acc[c][1], A, B), 0.f);
    float v2 = fmaxf(fmaf(acc[c][2], A, B), 0.f);
    float v3 = fmaxf(fmaf(acc[c][3], A, B), 0.f);
    float m = fmaxf(fmaxf(v0, v1), fmaxf(v2, v3));
    p1[((b * 64 + co) * 16 + py) * 16 + px] = m;
  }
}

// ---------------- k3: conv2 + BN + ReLU + pool + fused global fmax ----------------
__global__ __launch_bounds__(256) void k3_conv2(
    const float* __restrict__ p1, const float* __restrict__ w2t,
    const float* __restrict__ wsc, float* __restrict__ p2f,
    float* __restrict__ out, float* __restrict__ ws)
{
  __shared__ float in_s[32 * 324];  // 40.5 KB
  __shared__ float pb[4096];        // 16 KB pool buffer
  int tid = threadIdx.x;
  int b = blockIdx.x >> 3, cog = blockIdx.x & 7;
  int y = tid >> 4, xx = tid & 15;

  float acc[16];
#pragma unroll
  for (int c = 0; c < 16; ++c) acc[c] = 0.f;

  for (int h = 0; h < 2; ++h) {
    __syncthreads();
    for (int idx = tid; idx < 10368; idx += 256) {
      int ci = idx / 324, r = idx % 324, yy = r / 18, xc = r % 18;
      int yg = yy - 1, xg = xc - 1;
      float v = 0.f;
      if ((unsigned)yg < 16u && (unsigned)xg < 16u)
        v = p1[((b * 64 + h * 32 + ci) * 16 + yg) * 16 + xg];
      in_s[idx] = v;
    }
    __syncthreads();
    for (int ci = 0; ci < 32; ++ci) {
#pragma unroll
      for (int kk = 0; kk < 9; ++kk) {
        int ky = kk / 3, kx = kk % 3;
        float in = in_s[ci * 324 + (y + ky) * 18 + (xx + kx)];
        const float4* wp = (const float4*)(w2t + ((kk * 64 + h * 32 + ci) * 128 + cog * 16));
        float4 a0 = wp[0], a1 = wp[1], a2 = wp[2], a3 = wp[3];  // uniform -> s_load
        acc[0]  = fmaf(in, a0.x, acc[0]);  acc[1]  = fmaf(in, a0.y, acc[1]);
        acc[2]  = fmaf(in, a0.z, acc[2]);  acc[3]  = fmaf(in, a0.w, acc[3]);
        acc[4]  = fmaf(in, a1.x, acc[4]);  acc[5]  = fmaf(in, a1.y, acc[5]);
        acc[6]  = fmaf(in, a1.z, acc[6]);  acc[7]  = fmaf(in, a1.w, acc[7]);
        acc[8]  = fmaf(in, a2.x, acc[8]);  acc[9]  = fmaf(in, a2.y, acc[9]);
        acc[10] = fmaf(in, a2.z, acc[10]); acc[11] = fmaf(in, a2.w, acc[11]);
        acc[12] = fmaf(in, a3.x, acc[12]); acc[13] = fmaf(in, a3.y, acc[13]);
        acc[14] = fmaf(in, a3.z, acc[14]); acc[15] = fmaf(in, a3.w, acc[15]);
      }
    }
  }
  __syncthreads();
#pragma unroll
  for (int c = 0; c < 16; ++c) {
    int co = cog * 16 + c;
    float v = fmaxf(fmaf(acc[c], wsc[WS_BN + 128 + co], wsc[WS_BN + 256 + co]), 0.f);
    pb[c * 256 + y * 16 + xx] = v;
  }
  __syncthreads();
  if (tid < 64) {
    int py = tid >> 3, px = tid & 7;
    float lmax = 0.f;   // post-ReLU values >= 0
#pragma unroll
    for (int c = 0; c < 16; ++c) {
      const float* q = &pb[c * 256 + (2 * py) * 16 + 2 * px];
      float m = fmaxf(fmaxf(q[0], q[1]), fmaxf(q[16], q[17]));
      int co = cog * 16 + c;
      int fi = b * 8192 + co * 64 + py * 8 + px;
      p2f[fi] = m;
      out[32 + fi] = m;
      lmax = fmaxf(lmax, m);
    }
#pragma unroll
    for (int off = 32; off > 0; off >>= 1) lmax = fmaxf(lmax, __shfl_xor(lmax, off));
    if (tid == 0) atomicMax((int*)(ws + WS_FMAX), __float_as_int(lmax));
  }
}

// ---------------- k4: L1-kNN via v_sad_u8, wave-private no-barrier pipeline ----
// grid = (157 n-tiles of 128, 8 d-splits of 1024). 4 waves/block; wave w owns
// dims [s*1024 + w*256, +256) as 4 chunks of 64. Per-wave private LDS (no
// barriers in main loop): n tile [128][64B] u8 = 8 KB slot-XOR swizzled;
// f tile [32][64B] u8 = 2 KB. f quantized inline from p2f (L2-resident; k3c
// launch eliminated). nbr loads nontemporal (read-once stream, keeps p2f in L2).
__global__ __launch_bounds__(256) void k4_knn(
    const float* __restrict__ nbr, const float* __restrict__ p2f,
    const float* __restrict__ wsc, float* __restrict__ l1p)
{
  __shared__ __align__(16) char smem[40960];  // 4 x (8KB n + 2KB f)
  const int tid = threadIdx.x;
  const int w = tid >> 6, lane = tid & 63;
  const int b_lane = lane & 3;    // 0..3
  const int n_lane = lane >> 2;   // 0..15
  const int n0 = blockIdx.x * 128;
  const int s = blockIdx.y;
  const int dbase = s * 1024 + w * 256;
  char* nt = smem + w * 10240;
  char* ft = nt + 8192;
  const float kq = 255.0f / wsc[WS_FMAX];
  const int chi = (n_lane >> 1) & 3;   // read-side swizzle xor (j-invariant)

  unsigned acc[8][8];
#pragma unroll
  for (int i = 0; i < 8; ++i)
#pragma unroll
    for (int j = 0; j < 8; ++j) acc[i][j] = 0u;

#pragma unroll 1
  for (int ch = 0; ch < 4; ++ch) {
    const int dc = dbase + ch * 64;
    // ---- stage n: 128 rows x 64 dims fp32 -> u8 (nontemporal stream) ----
#pragma unroll 8
    for (int k = 0; k < 32; ++k) {
      int id = k * 64 + lane;
      int row = id >> 4, f4 = id & 15;
      int nn = n0 + row; if (nn > 19999) nn = 19999;
      f4v v = __builtin_nontemporal_load(
          (const f4v*)(nbr + (size_t)nn * 8192 + dc + f4 * 4));
      unsigned q0 = (unsigned)fmaf(v.x, kq, 0.5f);
      unsigned q1 = (unsigned)fmaf(v.y, kq, 0.5f);
      unsigned q2 = (unsigned)fmaf(v.z, kq, 0.5f);
      unsigned q3 = (unsigned)fmaf(v.w, kq, 0.5f);
      int slot = (f4 >> 2) ^ ((row >> 1) & 3);
      *(unsigned*)(nt + row * 64 + (slot << 4) + (f4 & 3) * 4) =
          q0 | (q1 << 8) | (q2 << 16) | (q3 << 24);
    }
    // ---- stage f: 32 rows x 64 dims fp32 (L2-hot) -> u8, unswizzled ----
#pragma unroll
    for (int k = 0; k < 8; ++k) {
      int id = k * 64 + lane;
      int row = id >> 4, f4 = id & 15;
      f4v v = *(const f4v*)(p2f + row * 8192 + dc + f4 * 4);
      unsigned q0 = (unsigned)fmaf(v.x, kq, 0.5f);
      unsigned q1 = (unsigned)fmaf(v.y, kq, 0.5f);
      unsigned q2 = (unsigned)fmaf(v.z, kq, 0.5f);
      unsigned q3 = (unsigned)fmaf(v.w, kq, 0.5f);
      *(unsigned*)(ft + row * 64 + f4 * 4) =
          q0 | (q1 << 8) | (q2 << 16) | (q3 << 24);
    }
    // ---- compute: 4 g-groups of 16 B; 8x8 pairs x uint4 sads ----
#pragma unroll
    for (int g = 0; g < 4; ++g) {
      const char* fb = ft + b_lane * 64 + g * 16;
      const char* nb = nt + n_lane * 64 + ((g ^ chi) << 4);
      uint4 fv[8], nv[8];
#pragma unroll
      for (int i = 0; i < 8; ++i) fv[i] = *(const uint4*)(fb + i * 256);
#pragma unroll
      for (int j = 0; j < 8; ++j) nv[j] = *(const uint4*)(nb + j * 1024);
#pragma unroll
      for (int i = 0; i < 8; ++i)
#pragma unroll
        for (int j = 0; j < 8; ++j) {
          unsigned t0 = sad4(fv[i].x, nv[j].x, acc[i][j]);
          t0 = sad4(fv[i].y, nv[j].y, t0);
          t0 = sad4(fv[i].z, nv[j].z, t0);
          acc[i][j] = sad4(fv[i].w, nv[j].w, t0);
        }
    }
  }

  // cross-wave reduce, 2 halves of 16 b-rows (32 KB overlay aliases tiles)
  unsigned* red = (unsigned*)smem;
#pragma unroll
  for (int r = 0; r < 2; ++r) {
    __syncthreads();
#pragma unroll
    for (int ii = 0; ii < 4; ++ii) {
#pragma unroll
      for (int j = 0; j < 8; ++j) {
        int b16 = b_lane + 4 * ii;            // 0..15 within this half
        int n = n_lane + 16 * j;
        red[(b16 * 128 + n) * 4 + w] = acc[r * 4 + ii][j];
      }
    }
    __syncthreads();
#pragma unroll
    for (int k = 0; k < 8; ++k) {
      int e = k * 256 + tid;                  // 0..2047
      uint4 v = *(const uint4*)(red + e * 4);
      int b = 16 * r + (e >> 7), n = e & 127;
      l1p[(s * 32 + b) * 20096 + n0 + n] = (float)(v.x + v.y + v.z + v.w);
    }
  }
}

// ---------------- k5: reduce splits, exp-weight, mask, last-block finalize ----
__global__ __launch_bounds__(256) void k5_final(
    const float* __restrict__ l1p, const int* __restrict__ labels,
    float* __restrict__ ws, float* __restrict__ out)
{
  __shared__ int islast;
  int b = blockIdx.y;
  int n = blockIdx.x * 256 + (int)threadIdx.x;
  // mode(labels) from the 20 histogram partials; ties -> smallest index
  const int* cp = (const int*)(ws + WS_CNTP);
  int best = 0, bc = -1;
#pragma unroll
  for (int c = 0; c < 10; ++c) {
    int sc = 0;
#pragma unroll
    for (int p = 0; p < 20; ++p) sc += cp[p * 10 + c];
    if (sc > bc) { bc = sc; best = c; }
  }
  float kc = ws[WS_FMAX] * (-1.0f / (255.0f * 1000.0f));
  float wgt = 0.f, mk = 0.f;
  if (n < 20000) {
    float L1 = 0.f;
#pragma unroll
    for (int s2 = 0; s2 < 8; ++s2) L1 += l1p[(s2 * 32 + b) * 20096 + n];
    wgt = __expf(L1 * kc);
    if (labels[n] == best) mk = wgt;
  }
#pragma unroll
  for (int off = 32; off > 0; off >>= 1) {
    wgt += __shfl_xor(wgt, off);
    mk  += __shfl_xor(mk, off);
  }
  float* nrdr = ws + WS_NR;
  if ((threadIdx.x & 63) == 0) {
    atomicAdd(&nrdr[b], mk);
    atomicAdd(&nrdr[32 + b], wgt);
  }
  __syncthreads();                      // all 4 waves' atomics drained (vmcnt)
  if (threadIdx.x == 0) {
    __threadfence();
    int total = gridDim.x * gridDim.y;  // 79*32 = 2528
    islast = (atomicAdd((int*)ws + WS_CTR, 1) == total - 1) ? 1 : 0;
  }
  __syncthreads();
  if (islast && threadIdx.x < 32) {
    float nr = atomicAdd(&nrdr[threadIdx.x], 0.f);        // coherent read-back
    float dr = atomicAdd(&nrdr[32 + threadIdx.x], 0.f);
    out[threadIdx.x] = nr / dr;
  }
}

extern "C" void kernel_launch(void* const* d_in, const int* in_sizes, int n_in,
                              void* d_out, int out_size, void* d_ws, size_t ws_size,
                              hipStream_t stream)
{
  (void)in_sizes; (void)n_in; (void)out_size; (void)ws_size;
  const float* x    = (const float*)d_in[0];
  const float* w1   = (const float*)d_in[1];
  const float* c1b  = (const float*)d_in[2];
  const float* g1   = (const float*)d_in[3];
  const float* be1  = (const float*)d_in[4];
  const float* m1   = (const float*)d_in[5];
  const float* v1   = (const float*)d_in[6];
  const float* w2   = (const float*)d_in[7];
  const float* c2b  = (const float*)d_in[8];
  const float* g2   = (const float*)d_in[9];
  const float* be2  = (const float*)d_in[10];
  const float* m2   = (const float*)d_in[11];
  const float* v2   = (const float*)d_in[12];
  const float* nbrf = (const float*)d_in[13];
  const int* labels = (const int*)d_in[14];
  float* ws = (float*)d_ws;
  float* out = (float*)d_out;

  prep<<<309, 256, 0, stream>>>(labels, w2, c1b, g1, be1, m1, v1,
                                c2b, g2, be2, m2, v2, ws);
  k2_conv1<<<512, 256, 0, stream>>>(x, w1, ws, ws + WS_P1);
  k3_conv2<<<256, 256, 0, stream>>>(ws + WS_P1, ws + WS_W2T, ws, ws + WS_P2F, out, ws);
  k4_knn<<<dim3(157, 8), 256, 0, stream>>>(nbrf, ws + WS_P2F, ws, ws + WS_L1P);
  k5_final<<<dim3(79, 32), 256, 0, stream>>>(ws + WS_L1P, labels, ws, out);
}